// Round 3
// baseline (3134.290 us; speedup 1.0000x reference)
//
#include <hip/hip_runtime.h>

typedef unsigned short u16;

#define NBATCH 16
#define NHEADS 12
#define BH 192
#define NSEQ 1025
#define NP 1024
#define HD 64
#define LM 256
#define INV_TAU 0.125f
#define MROWS 16400   // NBATCH*NSEQ

__device__ __forceinline__ float bf2f(u16 u){
  union { unsigned int i; float f; } x; x.i = ((unsigned int)u)<<16; return x.f;
}
__device__ __forceinline__ u16 f2bf(float f){
  union { float f; unsigned int i; } x; x.f = f;
  unsigned int r = x.i + 0x7fffu + ((x.i >> 16) & 1u);
  return (u16)(r >> 16);
}
__device__ __forceinline__ float ldf(const float* p){ return *p; }
__device__ __forceinline__ float ldf(const u16* p){ return bf2f(*p); }
__device__ __forceinline__ float4 ld4(const float* p){ return *(const float4*)p; }
__device__ __forceinline__ float4 ld4(const u16* p){
  uint2 u = *(const uint2*)p;
  return make_float4(bf2f((u16)u.x), bf2f((u16)(u.x>>16)),
                     bf2f((u16)u.y), bf2f((u16)(u.y>>16)));
}
__device__ __forceinline__ void stf(float* p, float v){ *p = v; }
__device__ __forceinline__ void stf(u16* p, float v){ *p = f2bf(v); }

// ---------------------------------------------------------------------------
// dtype probe: even-index u16s of fp32 data are mantissa halves (random exp);
// of bf16 data they are real small values. flag=1 -> inputs are bf16.
// ---------------------------------------------------------------------------
__global__ __launch_bounds__(256) void probe_dtype(const u16* __restrict__ x, int* flag)
{
  __shared__ int cnt;
  if (threadIdx.x == 0) cnt = 0;
  __syncthreads();
  int c = 0;
  #pragma unroll
  for (int j = 0; j < 8; ++j){
    u16 u = x[2*(threadIdx.x*8 + j)];
    int e = (u >> 7) & 0xFF;
    if (e >= 100 && e <= 140) c++;
  }
  atomicAdd(&cnt, c);
  __syncthreads();
  if (threadIdx.x == 0) *flag = (cnt > 1024) ? 1 : 0;
}

// ---------------------------------------------------------------------------
// xpool: x_pooled[b,l,c] = mean of 4 x rows (landmark pooling commutes with GEMM)
// ---------------------------------------------------------------------------
template<typename TIN>
__global__ __launch_bounds__(256) void xpool(
    const int* __restrict__ flag, int want,
    const TIN* __restrict__ X, float* __restrict__ XP)
{
  if (*flag != want) return;
  int idx = blockIdx.x*256 + threadIdx.x;          // (b*256+l)*768+c
  if (idx >= NBATCH*LM*768) return;
  int c = idx % 768;
  int l = (idx / 768) & 255;
  int b = idx / (768*256);
  int lr = l >> 4, lc = l & 15;
  int p = lr*64 + lc*2;                             // patch base; x row = 1+patch
  const TIN* xb = X + (size_t)b*NSEQ*768;
  XP[idx] = 0.25f*(ldf(xb + (size_t)(p+1)*768 + c) + ldf(xb + (size_t)(p+2)*768 + c)
                 + ldf(xb + (size_t)(p+33)*768 + c) + ldf(xb + (size_t)(p+34)*768 + c));
}

// ---------------------------------------------------------------------------
// lgemm: ql/kl = x_pooled(4096x768 f32) @ W[ob..ob+768)^T + bias -> (bh,256,64) f32
// ---------------------------------------------------------------------------
template<typename TIN>
__global__ __launch_bounds__(256) void lgemm(
    const int* __restrict__ flag, int want,
    const float* __restrict__ XP, const TIN* __restrict__ W, const TIN* __restrict__ Bias,
    int ob, float* __restrict__ OutL)
{
  if (*flag != want) return;
  __shared__ float As[16][68];
  __shared__ float Bs[16][68];
  const int t = threadIdx.x;
  const int m0 = blockIdx.x*64, o0 = blockIdx.y*64;
  const int tm = t>>4, tn = t&15;
  const int la_m = t>>2, la_k = (t&3)<<2;
  float acc[4][4] = {};
  const float* ap0 = XP + (size_t)(m0+la_m)*768 + la_k;
  const TIN* bp0 = W + (size_t)(ob+o0+la_m)*768 + la_k;
  for (int k0 = 0; k0 < 768; k0 += 16){
    float4 a4 = *(const float4*)(ap0 + k0);
    float4 b4 = ld4(bp0 + k0);
    As[la_k+0][la_m]=a4.x; As[la_k+1][la_m]=a4.y; As[la_k+2][la_m]=a4.z; As[la_k+3][la_m]=a4.w;
    Bs[la_k+0][la_m]=b4.x; Bs[la_k+1][la_m]=b4.y; Bs[la_k+2][la_m]=b4.z; Bs[la_k+3][la_m]=b4.w;
    __syncthreads();
    #pragma unroll
    for (int kk = 0; kk < 16; ++kk){
      float4 av = *(const float4*)&As[kk][tm<<2];
      float4 bv = *(const float4*)&Bs[kk][tn<<2];
      float ar[4]={av.x,av.y,av.z,av.w}, br[4]={bv.x,bv.y,bv.z,bv.w};
      #pragma unroll
      for (int ii=0;ii<4;ii++)
        #pragma unroll
        for (int jj=0;jj<4;jj++)
          acc[ii][jj] = fmaf(ar[ii], br[jj], acc[ii][jj]);
    }
    __syncthreads();
  }
  const int h = o0 >> 6;
  #pragma unroll
  for (int ii=0;ii<4;ii++){
    int m = m0 + (tm<<2) + ii;
    int b = m >> 8, l = m & 255;
    #pragma unroll
    for (int jj=0;jj<4;jj++){
      int d = (tn<<2) + jj;
      OutL[((size_t)(b*12+h)*256 + l)*64 + d] = acc[ii][jj] + ldf(Bias + ob + o0 + d);
    }
  }
}

// ---------------------------------------------------------------------------
// kvgemm: rows n=1..1024 of x @ W[768..2304)^T + bias -> kp/vp bf16 (bh,1024,64)
// ---------------------------------------------------------------------------
template<typename TIN>
__global__ __launch_bounds__(256) void kvgemm(
    const int* __restrict__ flag, int want,
    const TIN* __restrict__ X, const TIN* __restrict__ W, const TIN* __restrict__ Bias,
    u16* __restrict__ kp, u16* __restrict__ vp)
{
  if (*flag != want) return;
  __shared__ float As[16][68];
  __shared__ float Bs[16][68];
  const int t = threadIdx.x;
  const int m0 = blockIdx.x*64, o0 = blockIdx.y*64;   // m in [0,16384), o in [0,1536)
  const int tm = t>>4, tn = t&15;
  const int la_m = t>>2, la_k = (t&3)<<2;
  float acc[4][4] = {};
  int ar = m0 + la_m;
  int arb = ar >> 10, arn = ar & 1023;
  const TIN* ap0 = X + (size_t)(arb*1025 + arn + 1)*768 + la_k;
  const TIN* bp0 = W + (size_t)(768 + o0 + la_m)*768 + la_k;
  for (int k0 = 0; k0 < 768; k0 += 16){
    float4 a4 = ld4(ap0 + k0);
    float4 b4 = ld4(bp0 + k0);
    As[la_k+0][la_m]=a4.x; As[la_k+1][la_m]=a4.y; As[la_k+2][la_m]=a4.z; As[la_k+3][la_m]=a4.w;
    Bs[la_k+0][la_m]=b4.x; Bs[la_k+1][la_m]=b4.y; Bs[la_k+2][la_m]=b4.z; Bs[la_k+3][la_m]=b4.w;
    __syncthreads();
    #pragma unroll
    for (int kk = 0; kk < 16; ++kk){
      float4 av = *(const float4*)&As[kk][tm<<2];
      float4 bv = *(const float4*)&Bs[kk][tn<<2];
      float arr[4]={av.x,av.y,av.z,av.w}, brr[4]={bv.x,bv.y,bv.z,bv.w};
      #pragma unroll
      for (int ii=0;ii<4;ii++)
        #pragma unroll
        for (int jj=0;jj<4;jj++)
          acc[ii][jj] = fmaf(arr[ii], brr[jj], acc[ii][jj]);
    }
    __syncthreads();
  }
  const int isv = (o0 >= 768);
  const int h = ((o0 - (isv ? 768 : 0)) >> 6);
  u16* dst = isv ? vp : kp;
  #pragma unroll
  for (int ii=0;ii<4;ii++){
    int m = m0 + (tm<<2) + ii;
    int b = m >> 10, n1 = m & 1023;
    #pragma unroll
    for (int jj=0;jj<4;jj++){
      int d = (tn<<2) + jj;
      dst[((size_t)(b*12+h)*1024 + n1)*64 + d] = f2bf(acc[ii][jj] + ldf(Bias + 768 + o0 + d));
    }
  }
}

// ---------------------------------------------------------------------------
// qgemm: all 16400 rows of x @ W[0..768)^T + bias -> q fp32 (bh,1025,64)
// ---------------------------------------------------------------------------
template<typename TIN>
__global__ __launch_bounds__(256) void qgemm(
    const int* __restrict__ flag, int want,
    const TIN* __restrict__ X, const TIN* __restrict__ W, const TIN* __restrict__ Bias,
    float* __restrict__ q)
{
  if (*flag != want) return;
  __shared__ float As[16][68];
  __shared__ float Bs[16][68];
  const int t = threadIdx.x;
  const int m0 = blockIdx.x*64, o0 = blockIdx.y*64;
  const int tm = t>>4, tn = t&15;
  const int la_m = t>>2, la_k = (t&3)<<2;
  float acc[4][4] = {};
  int am = m0 + la_m; if (am > MROWS-1) am = MROWS-1;
  const TIN* ap0 = X + (size_t)am*768 + la_k;
  const TIN* bp0 = W + (size_t)(o0+la_m)*768 + la_k;
  for (int k0 = 0; k0 < 768; k0 += 16){
    float4 a4 = ld4(ap0 + k0);
    float4 b4 = ld4(bp0 + k0);
    As[la_k+0][la_m]=a4.x; As[la_k+1][la_m]=a4.y; As[la_k+2][la_m]=a4.z; As[la_k+3][la_m]=a4.w;
    Bs[la_k+0][la_m]=b4.x; Bs[la_k+1][la_m]=b4.y; Bs[la_k+2][la_m]=b4.z; Bs[la_k+3][la_m]=b4.w;
    __syncthreads();
    #pragma unroll
    for (int kk = 0; kk < 16; ++kk){
      float4 av = *(const float4*)&As[kk][tm<<2];
      float4 bv = *(const float4*)&Bs[kk][tn<<2];
      float arr[4]={av.x,av.y,av.z,av.w}, brr[4]={bv.x,bv.y,bv.z,bv.w};
      #pragma unroll
      for (int ii=0;ii<4;ii++)
        #pragma unroll
        for (int jj=0;jj<4;jj++)
          acc[ii][jj] = fmaf(arr[ii], brr[jj], acc[ii][jj]);
    }
    __syncthreads();
  }
  const int h = o0 >> 6;
  #pragma unroll
  for (int ii=0;ii<4;ii++){
    int m = m0 + (tm<<2) + ii;
    if (m >= MROWS) break;
    int b = m / 1025, n = m - b*1025;
    #pragma unroll
    for (int jj=0;jj<4;jj++){
      int d = (tn<<2) + jj;
      q[((size_t)(b*12+h)*1025 + n)*64 + d] = acc[ii][jj] + ldf(Bias + o0 + d);
    }
  }
}

// ---------------------------------------------------------------------------
// proj GEMM: y(f32 16400x768) @ proj_w^T + bias -> out (dtype = input dtype)
// ---------------------------------------------------------------------------
template<typename TIN>
__global__ __launch_bounds__(256) void projgemm(
    const int* __restrict__ flag, int want,
    const float* __restrict__ Y, const TIN* __restrict__ W, const TIN* __restrict__ Bias,
    TIN* __restrict__ Out)
{
  if (*flag != want) return;
  __shared__ float As[16][68];
  __shared__ float Bs[16][68];
  const int t = threadIdx.x;
  const int m0 = blockIdx.x*64, o0 = blockIdx.y*64;
  const int tm = t>>4, tn = t&15;
  const int la_m = t>>2, la_k = (t&3)<<2;
  float acc[4][4] = {};
  int am = m0 + la_m; if (am > MROWS-1) am = MROWS-1;
  const float* ap0 = Y + (size_t)am*768 + la_k;
  const TIN* bp0 = W + (size_t)(o0+la_m)*768 + la_k;
  for (int k0 = 0; k0 < 768; k0 += 16){
    float4 a4 = *(const float4*)(ap0 + k0);
    float4 b4 = ld4(bp0 + k0);
    As[la_k+0][la_m]=a4.x; As[la_k+1][la_m]=a4.y; As[la_k+2][la_m]=a4.z; As[la_k+3][la_m]=a4.w;
    Bs[la_k+0][la_m]=b4.x; Bs[la_k+1][la_m]=b4.y; Bs[la_k+2][la_m]=b4.z; Bs[la_k+3][la_m]=b4.w;
    __syncthreads();
    #pragma unroll
    for (int kk = 0; kk < 16; ++kk){
      float4 av = *(const float4*)&As[kk][tm<<2];
      float4 bv = *(const float4*)&Bs[kk][tn<<2];
      float arr[4]={av.x,av.y,av.z,av.w}, brr[4]={bv.x,bv.y,bv.z,bv.w};
      #pragma unroll
      for (int ii=0;ii<4;ii++)
        #pragma unroll
        for (int jj=0;jj<4;jj++)
          acc[ii][jj] = fmaf(arr[ii], brr[jj], acc[ii][jj]);
    }
    __syncthreads();
  }
  #pragma unroll
  for (int ii=0;ii<4;ii++){
    int m = m0 + (tm<<2) + ii;
    if (m >= MROWS) break;
    #pragma unroll
    for (int jj=0;jj<4;jj++){
      int o = o0 + (tn<<2) + jj;
      stf(Out + (size_t)m*768 + o, acc[ii][jj] + ldf(Bias + o));
    }
  }
}

// ---------------------------------------------------------------------------
// Batched GEMM: C[bh] = A(256x256) @ B(256xNDIM); MODE1: C = 2I - AB
// ---------------------------------------------------------------------------
template<int MODE, int NDIM>
__global__ __launch_bounds__(256) void bgemm(
    const float* __restrict__ A, const float* __restrict__ B, float* __restrict__ C)
{
  __shared__ float As[16][68];
  __shared__ float Bs[16][68];
  const int t = threadIdx.x;
  const int bh = blockIdx.x;
  const int i0 = blockIdx.y*64, j0 = blockIdx.z*64;
  const int tm = t>>4, tn = t&15;
  const float* Ab = A + (size_t)bh*65536;
  const float* Bb = B + (size_t)bh*256*NDIM;
  float* Cb = C + (size_t)bh*256*NDIM;
  const int la_m = t>>2, la_k = (t&3)<<2;
  const int lb_k = t>>4, lb_n = (t&15)<<2;
  float acc[4][4] = {};
  for (int k0 = 0; k0 < 256; k0 += 16){
    float4 a4 = *(const float4*)(Ab + (i0+la_m)*256 + k0 + la_k);
    As[la_k+0][la_m]=a4.x; As[la_k+1][la_m]=a4.y; As[la_k+2][la_m]=a4.z; As[la_k+3][la_m]=a4.w;
    *(float4*)&Bs[lb_k][lb_n] = *(const float4*)(Bb + (k0+lb_k)*NDIM + j0 + lb_n);
    __syncthreads();
    #pragma unroll
    for (int kk = 0; kk < 16; ++kk){
      float4 av = *(const float4*)&As[kk][tm<<2];
      float4 bv = *(const float4*)&Bs[kk][tn<<2];
      float arr[4]={av.x,av.y,av.z,av.w}, brr[4]={bv.x,bv.y,bv.z,bv.w};
      #pragma unroll
      for (int ii=0;ii<4;ii++)
        #pragma unroll
        for (int jj=0;jj<4;jj++)
          acc[ii][jj] = fmaf(arr[ii], brr[jj], acc[ii][jj]);
    }
    __syncthreads();
  }
  #pragma unroll
  for (int ii=0;ii<4;ii++){
    int i = i0 + (tm<<2) + ii;
    #pragma unroll
    for (int jj=0;jj<4;jj++){
      int j = j0 + (tn<<2) + jj;
      float v = acc[ii][jj];
      if (MODE == 1) v = ((i==j) ? 2.0f : 0.0f) - v;
      Cb[i*NDIM + j] = v;
    }
  }
}

// ---------------------------------------------------------------------------
// M2 = exp(-(|q|^2+|k|^2-2qk)/tau), (bh,256,256); ql/kl fp32
// ---------------------------------------------------------------------------
__global__ __launch_bounds__(256) void gauss_m2(
    const float* __restrict__ Q, const float* __restrict__ K,
    const float* __restrict__ qn, const float* __restrict__ kn, float* __restrict__ Out)
{
  __shared__ float Qs[64][68];
  __shared__ float Kst[64][66];
  const int bh = blockIdx.x, i0 = blockIdx.y*64, j0 = blockIdx.z*64;
  const int t = threadIdx.x, tm = t>>4, tn = t&15;
  #pragma unroll
  for (int e=0;e<4;e++){
    int f = e*256 + t; int r = f>>4; int c4 = (f&15)<<2;
    *(float4*)&Qs[r][c4] = *(const float4*)(Q + (size_t)(bh*256 + i0 + r)*64 + c4);
    float4 k4 = *(const float4*)(K + (size_t)(bh*256 + j0 + r)*64 + c4);
    Kst[c4+0][r]=k4.x; Kst[c4+1][r]=k4.y; Kst[c4+2][r]=k4.z; Kst[c4+3][r]=k4.w;
  }
  __syncthreads();
  float d[4][4] = {};
  for (int k0=0;k0<64;k0+=4){
    float qv[4][4], kv[4][4];
    #pragma unroll
    for (int ii=0;ii<4;ii++){
      float4 q4 = *(const float4*)&Qs[(tm<<2)+ii][k0];
      qv[ii][0]=q4.x; qv[ii][1]=q4.y; qv[ii][2]=q4.z; qv[ii][3]=q4.w;
    }
    #pragma unroll
    for (int kk=0;kk<4;kk++)
      #pragma unroll
      for (int jj=0;jj<4;jj++)
        kv[kk][jj] = Kst[k0+kk][(tn<<2)+jj];
    #pragma unroll
    for (int ii=0;ii<4;ii++)
      #pragma unroll
      for (int jj=0;jj<4;jj++){
        d[ii][jj] = fmaf(qv[ii][0], kv[0][jj], d[ii][jj]);
        d[ii][jj] = fmaf(qv[ii][1], kv[1][jj], d[ii][jj]);
        d[ii][jj] = fmaf(qv[ii][2], kv[2][jj], d[ii][jj]);
        d[ii][jj] = fmaf(qv[ii][3], kv[3][jj], d[ii][jj]);
      }
  }
  float qnr[4], knc[4];
  #pragma unroll
  for (int ii=0;ii<4;ii++) qnr[ii] = qn[bh*256 + i0 + (tm<<2) + ii];
  #pragma unroll
  for (int jj=0;jj<4;jj++) knc[jj] = kn[bh*256 + j0 + (tn<<2) + jj];
  #pragma unroll
  for (int ii=0;ii<4;ii++)
    #pragma unroll
    for (int jj=0;jj<4;jj++)
      Out[(size_t)(bh*256 + i0 + (tm<<2) + ii)*256 + j0 + (tn<<2) + jj] =
        __expf(-(qnr[ii] + knc[jj] - 2.0f*d[ii][jj]) * INV_TAU);
}

// ---------------------------------------------------------------------------
// Fused gauss + (S @ V). YMODE0: Out (bh,RQ,64); YMODE1: scatter (b,n,768)
// ---------------------------------------------------------------------------
template<int YMODE, int RQ, int RK, typename TQ, typename TK, typename TV>
__global__ __launch_bounds__(256) void gauss_av(
    const TQ* __restrict__ Q, const TK* __restrict__ Km,
    const TV* __restrict__ V, const float* __restrict__ qn,
    const float* __restrict__ kn, float* __restrict__ Out)
{
  __shared__ float Qs[64][68];
  __shared__ float Kst[64][66];
  __shared__ float Ss[64][68];
  const int bh = blockIdx.x, i0 = blockIdx.y*64;
  const int t = threadIdx.x, tm = t>>4, tn = t&15;
  #pragma unroll
  for (int e=0;e<4;e++){
    int f = e*256 + t; int r = f>>4; int c4 = (f&15)<<2;
    int gi = i0 + r; if (gi > RQ-1) gi = RQ-1;
    *(float4*)&Qs[r][c4] = ld4(Q + (size_t)(bh*RQ + gi)*64 + c4);
  }
  float qnr[4];
  #pragma unroll
  for (int ii=0;ii<4;ii++){ int gi = i0 + (tm<<2) + ii; if (gi > RQ-1) gi = RQ-1; qnr[ii] = qn[bh*RQ + gi]; }
  float acc[4][4] = {};
  for (int j0 = 0; j0 < RK; j0 += 64){
    __syncthreads();
    #pragma unroll
    for (int e=0;e<4;e++){
      int f = e*256 + t; int r = f>>4; int c4 = (f&15)<<2;
      float4 k4 = ld4(Km + (size_t)(bh*RK + j0 + r)*64 + c4);
      Kst[c4+0][r]=k4.x; Kst[c4+1][r]=k4.y; Kst[c4+2][r]=k4.z; Kst[c4+3][r]=k4.w;
    }
    __syncthreads();
    float d[4][4] = {};
    for (int k0=0;k0<64;k0+=4){
      float qv[4][4], kv[4][4];
      #pragma unroll
      for (int ii=0;ii<4;ii++){
        float4 q4 = *(const float4*)&Qs[(tm<<2)+ii][k0];
        qv[ii][0]=q4.x; qv[ii][1]=q4.y; qv[ii][2]=q4.z; qv[ii][3]=q4.w;
      }
      #pragma unroll
      for (int kk=0;kk<4;kk++)
        #pragma unroll
        for (int jj=0;jj<4;jj++)
          kv[kk][jj] = Kst[k0+kk][(tn<<2)+jj];
      #pragma unroll
      for (int ii=0;ii<4;ii++)
        #pragma unroll
        for (int jj=0;jj<4;jj++){
          d[ii][jj] = fmaf(qv[ii][0], kv[0][jj], d[ii][jj]);
          d[ii][jj] = fmaf(qv[ii][1], kv[1][jj], d[ii][jj]);
          d[ii][jj] = fmaf(qv[ii][2], kv[2][jj], d[ii][jj]);
          d[ii][jj] = fmaf(qv[ii][3], kv[3][jj], d[ii][jj]);
        }
    }
    float knc[4];
    #pragma unroll
    for (int jj=0;jj<4;jj++) knc[jj] = kn[bh*RK + j0 + (tn<<2) + jj];
    #pragma unroll
    for (int ii=0;ii<4;ii++)
      #pragma unroll
      for (int jj=0;jj<4;jj++)
        Ss[(tm<<2)+ii][(tn<<2)+jj] = __expf(-(qnr[ii] + knc[jj] - 2.0f*d[ii][jj]) * INV_TAU);
    __syncthreads();
    const TV* Vb = V + (size_t)(bh*RK + j0)*64;
    for (int c0=0;c0<64;c0+=4){
      float sv[4][4], vv[4][4];
      #pragma unroll
      for (int ii=0;ii<4;ii++){
        float4 s4 = *(const float4*)&Ss[(tm<<2)+ii][c0];
        sv[ii][0]=s4.x; sv[ii][1]=s4.y; sv[ii][2]=s4.z; sv[ii][3]=s4.w;
      }
      #pragma unroll
      for (int cc=0;cc<4;cc++){
        float4 v4 = ld4(Vb + (c0+cc)*64 + (tn<<2));
        vv[cc][0]=v4.x; vv[cc][1]=v4.y; vv[cc][2]=v4.z; vv[cc][3]=v4.w;
      }
      #pragma unroll
      for (int ii=0;ii<4;ii++)
        #pragma unroll
        for (int jj=0;jj<4;jj++){
          acc[ii][jj] = fmaf(sv[ii][0], vv[0][jj], acc[ii][jj]);
          acc[ii][jj] = fmaf(sv[ii][1], vv[1][jj], acc[ii][jj]);
          acc[ii][jj] = fmaf(sv[ii][2], vv[2][jj], acc[ii][jj]);
          acc[ii][jj] = fmaf(sv[ii][3], vv[3][jj], acc[ii][jj]);
        }
    }
  }
  #pragma unroll
  for (int ii=0;ii<4;ii++){
    int i = i0 + (tm<<2) + ii;
    if (i < RQ){
      if (YMODE){
        int b = bh / 12, h = bh - b*12;
        float* ob = Out + (size_t)(b*1025 + i)*768 + h*64 + (tn<<2);
        ob[0]=acc[ii][0]; ob[1]=acc[ii][1]; ob[2]=acc[ii][2]; ob[3]=acc[ii][3];
      } else {
        float* ob = Out + (size_t)(bh*RQ + i)*64 + (tn<<2);
        ob[0]=acc[ii][0]; ob[1]=acc[ii][1]; ob[2]=acc[ii][2]; ob[3]=acc[ii][3];
      }
    }
  }
}

// ---------------------------------------------------------------------------
template<typename T>
__global__ __launch_bounds__(256) void rownorm(
    const T* __restrict__ x, float* __restrict__ out, int rows)
{
  int gt = blockIdx.x*256 + threadIdx.x;
  int w = gt >> 6, lane = gt & 63;
  if (w >= rows) return;
  float v = ldf(x + (size_t)w*64 + lane);
  float s = v*v;
  #pragma unroll
  for (int off=32; off>0; off>>=1) s += __shfl_xor(s, off, 64);
  if (lane == 0) out[w] = s;
}

__global__ __launch_bounds__(256) void m2norm(
    const float* __restrict__ M2, float* __restrict__ nrm)
{
  __shared__ float red[256];
  int bh = blockIdx.x, i = threadIdx.x;
  const float* r = M2 + ((size_t)bh*256 + i)*256;
  float s = 0.f;
  for (int j=0;j<256;j++) s += fabsf(r[j]);
  red[i] = s; __syncthreads();
  for (int st=128; st>0; st>>=1){
    if (i < st) red[i] = fmaxf(red[i], red[i+st]);
    __syncthreads();
  }
  if (i == 0) nrm[bh] = red[0];
}

__global__ __launch_bounds__(256) void newton_init(
    const float* __restrict__ M2, const float* __restrict__ nrm, float* __restrict__ inv)
{
  __shared__ float T[64][65];
  int bh = blockIdx.x, i0 = blockIdx.y*64, j0 = blockIdx.z*64;
  float nn = nrm[bh];
  float sc = 1.0f/(nn*nn + 1e-6f);
  const float* Mb = M2 + (size_t)bh*65536;
  float* ob = inv + (size_t)bh*65536;
  int t = threadIdx.x;
  #pragma unroll
  for (int e=0;e<16;e++){ int f=e*256+t; int r=f>>6, c=f&63; T[r][c] = Mb[(i0+r)*256 + j0+c]; }
  __syncthreads();
  #pragma unroll
  for (int e=0;e<16;e++){ int f=e*256+t; int r=f>>6, c=f&63; ob[(j0+r)*256 + i0+c] = T[c][r]*sc; }
}

__global__ __launch_bounds__(256) void diag_fill(u16* out, int n, float val)
{
  int i = blockIdx.x*256 + threadIdx.x;
  if (i < n) out[i] = f2bf(val);
}

// ---------------------------------------------------------------------------
extern "C" void kernel_launch(void* const* d_in, const int* in_sizes, int n_in,
                              void* d_out, int out_size, void* d_ws, size_t ws_size,
                              hipStream_t stream)
{
  char* base = (char*)d_ws;
  size_t off = 0;
  auto A = [&](size_t bytes)->char*{ char* r = base + off; off += (bytes + 255) & ~(size_t)255; return r; };
  int*   flag = (int*)A(256);
  float* XP   = (float*)A((size_t)NBATCH*LM*768*4);     // x_pooled; later KV
  float* QL   = (float*)A((size_t)BH*LM*64*4);          // ql; later Vm
  float* KL   = (float*)A((size_t)BH*LM*64*4);
  char*  M2Y  = A((size_t)MROWS*768*4);                 // M2 (48MB); later y (50.4MB)
  char*  KPV  = A((size_t)MROWS*768*4);                 // kp+vp bf16; Newton temps; later q f32
  float* qn   = (float*)A((size_t)BH*NSEQ*4);
  float* qln  = (float*)A((size_t)BH*LM*4);
  float* kln  = (float*)A((size_t)BH*LM*4);
  float* kpn  = (float*)A((size_t)BH*NP*4);
  float* nrm  = (float*)A(256*4);
  if (ws_size < off){
    diag_fill<<<(out_size+255)/256, 256, 0, stream>>>((u16*)d_out, out_size, (float)(ws_size >> 20));
    return;
  }
  float* M2 = (float*)M2Y;
  float* y  = (float*)M2Y;
  float* KV = XP;
  float* Vm = QL;
  u16*   kp = (u16*)KPV;
  u16*   vp = (u16*)(KPV + (size_t)BH*NP*64*2);
  float* T0 = (float*)KPV;                 // Newton temps: 3 x 64*65536*4 = 48MB
  float* T1 = T0 + (size_t)64*65536;
  float* T2 = T0 + (size_t)128*65536;
  float* q  = (float*)KPV;                 // after Newton: q fp32 (50.38MB fits)

  // 0. dtype probe
  probe_dtype<<<1, 256, 0, stream>>>((const u16*)d_in[0], flag);

  #define DUAL(kernelcall_f, kernelcall_b) do { kernelcall_f; kernelcall_b; } while(0)
  const float* xf = (const float*)d_in[0]; const u16* xb = (const u16*)d_in[0];
  const float* wf = (const float*)d_in[1]; const u16* wb = (const u16*)d_in[1];
  const float* bf = (const float*)d_in[2]; const u16* bb = (const u16*)d_in[2];
  const float* pwf= (const float*)d_in[3]; const u16* pwb= (const u16*)d_in[3];
  const float* pbf= (const float*)d_in[4]; const u16* pbb= (const u16*)d_in[4];

  // 1. x_pooled
  DUAL((xpool<float><<<(NBATCH*LM*768)/256,256,0,stream>>>(flag,0,xf,XP)),
       (xpool<u16>  <<<(NBATCH*LM*768)/256,256,0,stream>>>(flag,1,xb,XP)));
  // 2. ql, kl (landmarks via pooled-x GEMM; exact by linearity)
  DUAL((lgemm<float><<<dim3(64,12),256,0,stream>>>(flag,0,XP,wf,bf,0,QL)),
       (lgemm<u16>  <<<dim3(64,12),256,0,stream>>>(flag,1,XP,wb,bb,0,QL)));
  DUAL((lgemm<float><<<dim3(64,12),256,0,stream>>>(flag,0,XP,wf,bf,768,KL)),
       (lgemm<u16>  <<<dim3(64,12),256,0,stream>>>(flag,1,XP,wb,bb,768,KL)));
  // 3. landmark norms + M2 + its norm
  rownorm<float><<<(BH*LM*64)/256,256,0,stream>>>(QL, qln, BH*LM);
  rownorm<float><<<(BH*LM*64)/256,256,0,stream>>>(KL, kln, BH*LM);
  gauss_m2<<<dim3(BH,4,4),256,0,stream>>>(QL, KL, qln, kln, M2);
  m2norm<<<BH,256,0,stream>>>(M2, nrm);
  // 4. kp, vp (bf16)
  DUAL((kvgemm<float><<<dim3(256,24),256,0,stream>>>(flag,0,xf,wf,bf,kp,vp)),
       (kvgemm<u16>  <<<dim3(256,24),256,0,stream>>>(flag,1,xb,wb,bb,kp,vp)));
  rownorm<u16><<<(BH*NP*64)/256,256,0,stream>>>(kp, kpn, BH*NP);
  // 5. KV = gauss(ql, kp) @ vp   (overlays dead x_pooled)
  gauss_av<0,256,1024,float,u16,u16><<<dim3(BH,4),256,0,stream>>>(QL, kp, vp, qln, kpn, KV);
  // 6. Newton (3 groups of 64; temps overlay dead kp+vp) + V_mixed
  for (int g = 0; g < 3; ++g){
    const float* M2g = M2 + (size_t)g*64*65536;
    newton_init<<<dim3(64,4,4),256,0,stream>>>(M2g, nrm + g*64, T0);
    float* cur = T0; float* nxt = T2;
    for (int it = 0; it < 6; ++it){
      bgemm<1,256><<<dim3(64,4,4),256,0,stream>>>(M2g, cur, T1);
      bgemm<0,256><<<dim3(64,4,4),256,0,stream>>>(cur, T1, nxt);
      float* tt = cur; cur = nxt; nxt = tt;
    }
    bgemm<0,64><<<dim3(64,4,1),256,0,stream>>>(cur, KV + (size_t)g*64*16384,
                                               Vm + (size_t)g*64*16384);
  }
  // 7. q fp32 (overlays dead Newton temps) + qn
  DUAL((qgemm<float><<<dim3(257,12),256,0,stream>>>(flag,0,xf,wf,bf,q)),
       (qgemm<u16>  <<<dim3(257,12),256,0,stream>>>(flag,1,xb,wb,bb,q)));
  rownorm<float><<<(BH*NSEQ*64+255)/256*1,256,0,stream>>>(q, qn, BH*NSEQ);
  // 8. y = gauss(q, kl) @ V_mixed -> (b,n,768) fp32 (overlays dead M2)
  gauss_av<1,1025,256,float,float,float><<<dim3(BH,17),256,0,stream>>>(q, KL, Vm, qn, kln, y);
  // 9. out = y @ proj_w^T + proj_b (out dtype per flag)
  DUAL((projgemm<float><<<dim3(257,12),256,0,stream>>>(flag,0,y,pwf,pbf,(float*)d_out)),
       (projgemm<u16>  <<<dim3(257,12),256,0,stream>>>(flag,1,y,pwb,pbb,(u16*)d_out)));
}

// Round 4
// 2815.945 us; speedup vs baseline: 1.1131x; 1.1131x over previous
//
#include <hip/hip_runtime.h>

typedef unsigned short u16;

#define NBATCH 16
#define NHEADS 12
#define BH 192
#define NSEQ 1025
#define NP 1024
#define HD 64
#define LM 256
#define INV_TAU 0.125f
#define MROWS 16400   // NBATCH*NSEQ

__device__ __forceinline__ float bf2f(u16 u){
  union { unsigned int i; float f; } x; x.i = ((unsigned int)u)<<16; return x.f;
}
__device__ __forceinline__ u16 f2bf(float f){
  union { float f; unsigned int i; } x; x.f = f;
  unsigned int r = x.i + 0x7fffu + ((x.i >> 16) & 1u);
  return (u16)(r >> 16);
}
__device__ __forceinline__ float ldf(const float* p){ return *p; }
__device__ __forceinline__ float ldf(const u16* p){ return bf2f(*p); }
__device__ __forceinline__ float4 ld4(const float* p){ return *(const float4*)p; }
__device__ __forceinline__ float4 ld4(const u16* p){
  uint2 u = *(const uint2*)p;
  return make_float4(bf2f((u16)u.x), bf2f((u16)(u.x>>16)),
                     bf2f((u16)u.y), bf2f((u16)(u.y>>16)));
}
__device__ __forceinline__ void stf(float* p, float v){ *p = v; }
__device__ __forceinline__ void stf(u16* p, float v){ *p = f2bf(v); }

// ---------------------------------------------------------------------------
// dtype probe
// ---------------------------------------------------------------------------
__global__ __launch_bounds__(256) void probe_dtype(const u16* __restrict__ x, int* flag)
{
  __shared__ int cnt;
  if (threadIdx.x == 0) cnt = 0;
  __syncthreads();
  int c = 0;
  #pragma unroll
  for (int j = 0; j < 8; ++j){
    u16 u = x[2*(threadIdx.x*8 + j)];
    int e = (u >> 7) & 0xFF;
    if (e >= 100 && e <= 140) c++;
  }
  atomicAdd(&cnt, c);
  __syncthreads();
  if (threadIdx.x == 0) *flag = (cnt > 1024) ? 1 : 0;
}

// ---------------------------------------------------------------------------
// xpool
// ---------------------------------------------------------------------------
template<typename TIN>
__global__ __launch_bounds__(256) void xpool(
    const int* __restrict__ flag, int want,
    const TIN* __restrict__ X, float* __restrict__ XP)
{
  if (*flag != want) return;
  int idx = blockIdx.x*256 + threadIdx.x;
  if (idx >= NBATCH*LM*768) return;
  int c = idx % 768;
  int l = (idx / 768) & 255;
  int b = idx / (768*256);
  int lr = l >> 4, lc = l & 15;
  int p = lr*64 + lc*2;
  const TIN* xb = X + (size_t)b*NSEQ*768;
  XP[idx] = 0.25f*(ldf(xb + (size_t)(p+1)*768 + c) + ldf(xb + (size_t)(p+2)*768 + c)
                 + ldf(xb + (size_t)(p+33)*768 + c) + ldf(xb + (size_t)(p+34)*768 + c));
}

// ---------------------------------------------------------------------------
// lgemm
// ---------------------------------------------------------------------------
template<typename TIN>
__global__ __launch_bounds__(256) void lgemm(
    const int* __restrict__ flag, int want,
    const float* __restrict__ XP, const TIN* __restrict__ W, const TIN* __restrict__ Bias,
    int ob, float* __restrict__ OutL)
{
  if (*flag != want) return;
  __shared__ float As[16][68];
  __shared__ float Bs[16][68];
  const int t = threadIdx.x;
  const int m0 = blockIdx.x*64, o0 = blockIdx.y*64;
  const int tm = t>>4, tn = t&15;
  const int la_m = t>>2, la_k = (t&3)<<2;
  float acc[4][4] = {};
  const float* ap0 = XP + (size_t)(m0+la_m)*768 + la_k;
  const TIN* bp0 = W + (size_t)(ob+o0+la_m)*768 + la_k;
  for (int k0 = 0; k0 < 768; k0 += 16){
    float4 a4 = *(const float4*)(ap0 + k0);
    float4 b4 = ld4(bp0 + k0);
    As[la_k+0][la_m]=a4.x; As[la_k+1][la_m]=a4.y; As[la_k+2][la_m]=a4.z; As[la_k+3][la_m]=a4.w;
    Bs[la_k+0][la_m]=b4.x; Bs[la_k+1][la_m]=b4.y; Bs[la_k+2][la_m]=b4.z; Bs[la_k+3][la_m]=b4.w;
    __syncthreads();
    #pragma unroll
    for (int kk = 0; kk < 16; ++kk){
      float4 av = *(const float4*)&As[kk][tm<<2];
      float4 bv = *(const float4*)&Bs[kk][tn<<2];
      float ar[4]={av.x,av.y,av.z,av.w}, br[4]={bv.x,bv.y,bv.z,bv.w};
      #pragma unroll
      for (int ii=0;ii<4;ii++)
        #pragma unroll
        for (int jj=0;jj<4;jj++)
          acc[ii][jj] = fmaf(ar[ii], br[jj], acc[ii][jj]);
    }
    __syncthreads();
  }
  const int h = o0 >> 6;
  #pragma unroll
  for (int ii=0;ii<4;ii++){
    int m = m0 + (tm<<2) + ii;
    int b = m >> 8, l = m & 255;
    #pragma unroll
    for (int jj=0;jj<4;jj++){
      int d = (tn<<2) + jj;
      OutL[((size_t)(b*12+h)*256 + l)*64 + d] = acc[ii][jj] + ldf(Bias + ob + o0 + d);
    }
  }
}

// ---------------------------------------------------------------------------
// kvgemm
// ---------------------------------------------------------------------------
template<typename TIN>
__global__ __launch_bounds__(256) void kvgemm(
    const int* __restrict__ flag, int want,
    const TIN* __restrict__ X, const TIN* __restrict__ W, const TIN* __restrict__ Bias,
    u16* __restrict__ kp, u16* __restrict__ vp)
{
  if (*flag != want) return;
  __shared__ float As[16][68];
  __shared__ float Bs[16][68];
  const int t = threadIdx.x;
  const int m0 = blockIdx.x*64, o0 = blockIdx.y*64;
  const int tm = t>>4, tn = t&15;
  const int la_m = t>>2, la_k = (t&3)<<2;
  float acc[4][4] = {};
  int ar = m0 + la_m;
  int arb = ar >> 10, arn = ar & 1023;
  const TIN* ap0 = X + (size_t)(arb*1025 + arn + 1)*768 + la_k;
  const TIN* bp0 = W + (size_t)(768 + o0 + la_m)*768 + la_k;
  for (int k0 = 0; k0 < 768; k0 += 16){
    float4 a4 = ld4(ap0 + k0);
    float4 b4 = ld4(bp0 + k0);
    As[la_k+0][la_m]=a4.x; As[la_k+1][la_m]=a4.y; As[la_k+2][la_m]=a4.z; As[la_k+3][la_m]=a4.w;
    Bs[la_k+0][la_m]=b4.x; Bs[la_k+1][la_m]=b4.y; Bs[la_k+2][la_m]=b4.z; Bs[la_k+3][la_m]=b4.w;
    __syncthreads();
    #pragma unroll
    for (int kk = 0; kk < 16; ++kk){
      float4 av = *(const float4*)&As[kk][tm<<2];
      float4 bv = *(const float4*)&Bs[kk][tn<<2];
      float arr[4]={av.x,av.y,av.z,av.w}, brr[4]={bv.x,bv.y,bv.z,bv.w};
      #pragma unroll
      for (int ii=0;ii<4;ii++)
        #pragma unroll
        for (int jj=0;jj<4;jj++)
          acc[ii][jj] = fmaf(arr[ii], brr[jj], acc[ii][jj]);
    }
    __syncthreads();
  }
  const int isv = (o0 >= 768);
  const int h = ((o0 - (isv ? 768 : 0)) >> 6);
  u16* dst = isv ? vp : kp;
  #pragma unroll
  for (int ii=0;ii<4;ii++){
    int m = m0 + (tm<<2) + ii;
    int b = m >> 10, n1 = m & 1023;
    #pragma unroll
    for (int jj=0;jj<4;jj++){
      int d = (tn<<2) + jj;
      dst[((size_t)(b*12+h)*1024 + n1)*64 + d] = f2bf(acc[ii][jj] + ldf(Bias + 768 + o0 + d));
    }
  }
}

// ---------------------------------------------------------------------------
// qgemm
// ---------------------------------------------------------------------------
template<typename TIN>
__global__ __launch_bounds__(256) void qgemm(
    const int* __restrict__ flag, int want,
    const TIN* __restrict__ X, const TIN* __restrict__ W, const TIN* __restrict__ Bias,
    float* __restrict__ q)
{
  if (*flag != want) return;
  __shared__ float As[16][68];
  __shared__ float Bs[16][68];
  const int t = threadIdx.x;
  const int m0 = blockIdx.x*64, o0 = blockIdx.y*64;
  const int tm = t>>4, tn = t&15;
  const int la_m = t>>2, la_k = (t&3)<<2;
  float acc[4][4] = {};
  int am = m0 + la_m; if (am > MROWS-1) am = MROWS-1;
  const TIN* ap0 = X + (size_t)am*768 + la_k;
  const TIN* bp0 = W + (size_t)(o0+la_m)*768 + la_k;
  for (int k0 = 0; k0 < 768; k0 += 16){
    float4 a4 = ld4(ap0 + k0);
    float4 b4 = ld4(bp0 + k0);
    As[la_k+0][la_m]=a4.x; As[la_k+1][la_m]=a4.y; As[la_k+2][la_m]=a4.z; As[la_k+3][la_m]=a4.w;
    Bs[la_k+0][la_m]=b4.x; Bs[la_k+1][la_m]=b4.y; Bs[la_k+2][la_m]=b4.z; Bs[la_k+3][la_m]=b4.w;
    __syncthreads();
    #pragma unroll
    for (int kk = 0; kk < 16; ++kk){
      float4 av = *(const float4*)&As[kk][tm<<2];
      float4 bv = *(const float4*)&Bs[kk][tn<<2];
      float arr[4]={av.x,av.y,av.z,av.w}, brr[4]={bv.x,bv.y,bv.z,bv.w};
      #pragma unroll
      for (int ii=0;ii<4;ii++)
        #pragma unroll
        for (int jj=0;jj<4;jj++)
          acc[ii][jj] = fmaf(arr[ii], brr[jj], acc[ii][jj]);
    }
    __syncthreads();
  }
  const int h = o0 >> 6;
  #pragma unroll
  for (int ii=0;ii<4;ii++){
    int m = m0 + (tm<<2) + ii;
    if (m >= MROWS) break;
    int b = m / 1025, n = m - b*1025;
    #pragma unroll
    for (int jj=0;jj<4;jj++){
      int d = (tn<<2) + jj;
      q[((size_t)(b*12+h)*1025 + n)*64 + d] = acc[ii][jj] + ldf(Bias + o0 + d);
    }
  }
}

// ---------------------------------------------------------------------------
// projgemm
// ---------------------------------------------------------------------------
template<typename TIN>
__global__ __launch_bounds__(256) void projgemm(
    const int* __restrict__ flag, int want,
    const float* __restrict__ Y, const TIN* __restrict__ W, const TIN* __restrict__ Bias,
    TIN* __restrict__ Out)
{
  if (*flag != want) return;
  __shared__ float As[16][68];
  __shared__ float Bs[16][68];
  const int t = threadIdx.x;
  const int m0 = blockIdx.x*64, o0 = blockIdx.y*64;
  const int tm = t>>4, tn = t&15;
  const int la_m = t>>2, la_k = (t&3)<<2;
  float acc[4][4] = {};
  int am = m0 + la_m; if (am > MROWS-1) am = MROWS-1;
  const float* ap0 = Y + (size_t)am*768 + la_k;
  const TIN* bp0 = W + (size_t)(o0+la_m)*768 + la_k;
  for (int k0 = 0; k0 < 768; k0 += 16){
    float4 a4 = *(const float4*)(ap0 + k0);
    float4 b4 = ld4(bp0 + k0);
    As[la_k+0][la_m]=a4.x; As[la_k+1][la_m]=a4.y; As[la_k+2][la_m]=a4.z; As[la_k+3][la_m]=a4.w;
    Bs[la_k+0][la_m]=b4.x; Bs[la_k+1][la_m]=b4.y; Bs[la_k+2][la_m]=b4.z; Bs[la_k+3][la_m]=b4.w;
    __syncthreads();
    #pragma unroll
    for (int kk = 0; kk < 16; ++kk){
      float4 av = *(const float4*)&As[kk][tm<<2];
      float4 bv = *(const float4*)&Bs[kk][tn<<2];
      float arr[4]={av.x,av.y,av.z,av.w}, brr[4]={bv.x,bv.y,bv.z,bv.w};
      #pragma unroll
      for (int ii=0;ii<4;ii++)
        #pragma unroll
        for (int jj=0;jj<4;jj++)
          acc[ii][jj] = fmaf(arr[ii], brr[jj], acc[ii][jj]);
    }
    __syncthreads();
  }
  #pragma unroll
  for (int ii=0;ii<4;ii++){
    int m = m0 + (tm<<2) + ii;
    if (m >= MROWS) break;
    #pragma unroll
    for (int jj=0;jj<4;jj++){
      int o = o0 + (tn<<2) + jj;
      stf(Out + (size_t)m*768 + o, acc[ii][jj] + ldf(Bias + o));
    }
  }
}

// ---------------------------------------------------------------------------
// mgemm: MFMA split-bf16 batched GEMM, per-bh C(256x256) = A @ B (+MODE1: 2I-AB)
// hi/lo split => ~fp32 precision at bf16 MFMA rate/3.
// Block: 64x64 tile, BK=32, 4 waves (2x2), wave = 2x2 MFMA tiles of 16x16x32.
// LDS in exact fragment order: [tile][lane][j] -> conflict-free ds_read_b128.
// ---------------------------------------------------------------------------
typedef __attribute__((ext_vector_type(8))) short s8v;
typedef __attribute__((ext_vector_type(4))) float f4v;

template<int MODE>
__global__ __launch_bounds__(256) void mgemm(
    const float* __restrict__ A, const float* __restrict__ B, float* __restrict__ C)
{
  __shared__ u16 Ah[4*64*8], Al[4*64*8];
  __shared__ u16 Bh[4*64*8], Bl[4*64*8];
  const int t = threadIdx.x;
  const int bh = blockIdx.x;
  const int i0 = blockIdx.y*64, j0 = blockIdx.z*64;
  const float* Ab = A + (size_t)bh*65536;
  const float* Bb = B + (size_t)bh*65536;
  float* Cb = C + (size_t)bh*65536;
  const int lane = t & 63, wave = t >> 6;
  const int wr = wave >> 1, wc = wave & 1;

  f4v acc[2][2];
  #pragma unroll
  for (int a=0;a<2;a++)
    #pragma unroll
    for (int b=0;b<2;b++) acc[a][b] = (f4v){0.f,0.f,0.f,0.f};

  for (int k0 = 0; k0 < 256; k0 += 32){
    // stage A tile (64 x 32): 512 float4, 2 per thread
    #pragma unroll
    for (int e = 0; e < 2; ++e){
      int f = e*256 + t;
      int r = f >> 3, c4 = (f & 7) << 2;          // row, col-of-4
      float4 ga = *(const float4*)(Ab + (size_t)(i0+r)*256 + k0 + c4);
      int tile = r >> 4, m = r & 15, quad = c4 >> 3, jq = c4 & 7;
      int dst = ((tile*64 + quad*16 + m)*8 + jq);
      float va[4] = {ga.x, ga.y, ga.z, ga.w};
      ushort4 h4, l4;
      u16 h;
      h = f2bf(va[0]); h4.x = h; l4.x = f2bf(va[0]-bf2f(h));
      h = f2bf(va[1]); h4.y = h; l4.y = f2bf(va[1]-bf2f(h));
      h = f2bf(va[2]); h4.z = h; l4.z = f2bf(va[2]-bf2f(h));
      h = f2bf(va[3]); h4.w = h; l4.w = f2bf(va[3]-bf2f(h));
      *(ushort4*)&Ah[dst] = h4;
      *(ushort4*)&Al[dst] = l4;
    }
    // stage B tile (32 x 64): 512 float4, 2 per thread; scatter b16 per elem
    #pragma unroll
    for (int e = 0; e < 2; ++e){
      int f = e*256 + t;
      int k = f >> 4, c4 = (f & 15) << 2;         // k-row, n-col-of-4
      float4 gb = *(const float4*)(Bb + (size_t)(k0+k)*256 + j0 + c4);
      int quad = k >> 3, j = k & 7;
      float vb[4] = {gb.x, gb.y, gb.z, gb.w};
      #pragma unroll
      for (int s = 0; s < 4; ++s){
        int n = c4 + s;
        int idx = (((n>>4)*64 + quad*16 + (n&15))*8 + j);
        u16 h = f2bf(vb[s]);
        Bh[idx] = h;
        Bl[idx] = f2bf(vb[s] - bf2f(h));
      }
    }
    __syncthreads();
    s8v ah[2], al[2], bhf[2], blf[2];
    #pragma unroll
    for (int rt = 0; rt < 2; ++rt){
      int gt = wr*2 + rt;
      ah[rt] = *(const s8v*)&Ah[(gt*64 + lane)*8];
      al[rt] = *(const s8v*)&Al[(gt*64 + lane)*8];
    }
    #pragma unroll
    for (int ct = 0; ct < 2; ++ct){
      int gt = wc*2 + ct;
      bhf[ct] = *(const s8v*)&Bh[(gt*64 + lane)*8];
      blf[ct] = *(const s8v*)&Bl[(gt*64 + lane)*8];
    }
    #pragma unroll
    for (int rt = 0; rt < 2; ++rt)
      #pragma unroll
      for (int ct = 0; ct < 2; ++ct){
        acc[rt][ct] = __builtin_amdgcn_mfma_f32_16x16x32_bf16(ah[rt], bhf[ct], acc[rt][ct], 0,0,0);
        acc[rt][ct] = __builtin_amdgcn_mfma_f32_16x16x32_bf16(al[rt], bhf[ct], acc[rt][ct], 0,0,0);
        acc[rt][ct] = __builtin_amdgcn_mfma_f32_16x16x32_bf16(ah[rt], blf[ct], acc[rt][ct], 0,0,0);
      }
    __syncthreads();
  }
  // epilogue: C/D layout col=lane&15, row=(lane>>4)*4+reg
  #pragma unroll
  for (int rt = 0; rt < 2; ++rt)
    #pragma unroll
    for (int ct = 0; ct < 2; ++ct){
      int col = j0 + (wc*2+ct)*16 + (lane & 15);
      int rbase = i0 + (wr*2+rt)*16 + (lane >> 4)*4;
      #pragma unroll
      for (int r = 0; r < 4; ++r){
        int row = rbase + r;
        float v = acc[rt][ct][r];
        if (MODE == 1) v = ((row==col) ? 2.0f : 0.0f) - v;
        Cb[(size_t)row*256 + col] = v;
      }
    }
}

// ---------------------------------------------------------------------------
// bgemm (kept for NDIM=64 tail): C[bh] = A(256x256) @ B(256x64)
// ---------------------------------------------------------------------------
template<int MODE, int NDIM>
__global__ __launch_bounds__(256) void bgemm(
    const float* __restrict__ A, const float* __restrict__ B, float* __restrict__ C)
{
  __shared__ float As[16][68];
  __shared__ float Bs[16][68];
  const int t = threadIdx.x;
  const int bh = blockIdx.x;
  const int i0 = blockIdx.y*64, j0 = blockIdx.z*64;
  const int tm = t>>4, tn = t&15;
  const float* Ab = A + (size_t)bh*65536;
  const float* Bb = B + (size_t)bh*256*NDIM;
  float* Cb = C + (size_t)bh*256*NDIM;
  const int la_m = t>>2, la_k = (t&3)<<2;
  const int lb_k = t>>4, lb_n = (t&15)<<2;
  float acc[4][4] = {};
  for (int k0 = 0; k0 < 256; k0 += 16){
    float4 a4 = *(const float4*)(Ab + (i0+la_m)*256 + k0 + la_k);
    As[la_k+0][la_m]=a4.x; As[la_k+1][la_m]=a4.y; As[la_k+2][la_m]=a4.z; As[la_k+3][la_m]=a4.w;
    *(float4*)&Bs[lb_k][lb_n] = *(const float4*)(Bb + (k0+lb_k)*NDIM + j0 + lb_n);
    __syncthreads();
    #pragma unroll
    for (int kk = 0; kk < 16; ++kk){
      float4 av = *(const float4*)&As[kk][tm<<2];
      float4 bv = *(const float4*)&Bs[kk][tn<<2];
      float arr[4]={av.x,av.y,av.z,av.w}, brr[4]={bv.x,bv.y,bv.z,bv.w};
      #pragma unroll
      for (int ii=0;ii<4;ii++)
        #pragma unroll
        for (int jj=0;jj<4;jj++)
          acc[ii][jj] = fmaf(arr[ii], brr[jj], acc[ii][jj]);
    }
    __syncthreads();
  }
  #pragma unroll
  for (int ii=0;ii<4;ii++){
    int i = i0 + (tm<<2) + ii;
    #pragma unroll
    for (int jj=0;jj<4;jj++){
      int j = j0 + (tn<<2) + jj;
      float v = acc[ii][jj];
      if (MODE == 1) v = ((i==j) ? 2.0f : 0.0f) - v;
      Cb[i*NDIM + j] = v;
    }
  }
}

// ---------------------------------------------------------------------------
// gauss_m2
// ---------------------------------------------------------------------------
__global__ __launch_bounds__(256) void gauss_m2(
    const float* __restrict__ Q, const float* __restrict__ K,
    const float* __restrict__ qn, const float* __restrict__ kn, float* __restrict__ Out)
{
  __shared__ float Qs[64][68];
  __shared__ float Kst[64][66];
  const int bh = blockIdx.x, i0 = blockIdx.y*64, j0 = blockIdx.z*64;
  const int t = threadIdx.x, tm = t>>4, tn = t&15;
  #pragma unroll
  for (int e=0;e<4;e++){
    int f = e*256 + t; int r = f>>4; int c4 = (f&15)<<2;
    *(float4*)&Qs[r][c4] = *(const float4*)(Q + (size_t)(bh*256 + i0 + r)*64 + c4);
    float4 k4 = *(const float4*)(K + (size_t)(bh*256 + j0 + r)*64 + c4);
    Kst[c4+0][r]=k4.x; Kst[c4+1][r]=k4.y; Kst[c4+2][r]=k4.z; Kst[c4+3][r]=k4.w;
  }
  __syncthreads();
  float d[4][4] = {};
  for (int k0=0;k0<64;k0+=4){
    float qv[4][4], kv[4][4];
    #pragma unroll
    for (int ii=0;ii<4;ii++){
      float4 q4 = *(const float4*)&Qs[(tm<<2)+ii][k0];
      qv[ii][0]=q4.x; qv[ii][1]=q4.y; qv[ii][2]=q4.z; qv[ii][3]=q4.w;
    }
    #pragma unroll
    for (int kk=0;kk<4;kk++)
      #pragma unroll
      for (int jj=0;jj<4;jj++)
        kv[kk][jj] = Kst[k0+kk][(tn<<2)+jj];
    #pragma unroll
    for (int ii=0;ii<4;ii++)
      #pragma unroll
      for (int jj=0;jj<4;jj++){
        d[ii][jj] = fmaf(qv[ii][0], kv[0][jj], d[ii][jj]);
        d[ii][jj] = fmaf(qv[ii][1], kv[1][jj], d[ii][jj]);
        d[ii][jj] = fmaf(qv[ii][2], kv[2][jj], d[ii][jj]);
        d[ii][jj] = fmaf(qv[ii][3], kv[3][jj], d[ii][jj]);
      }
  }
  float qnr[4], knc[4];
  #pragma unroll
  for (int ii=0;ii<4;ii++) qnr[ii] = qn[bh*256 + i0 + (tm<<2) + ii];
  #pragma unroll
  for (int jj=0;jj<4;jj++) knc[jj] = kn[bh*256 + j0 + (tn<<2) + jj];
  #pragma unroll
  for (int ii=0;ii<4;ii++)
    #pragma unroll
    for (int jj=0;jj<4;jj++)
      Out[(size_t)(bh*256 + i0 + (tm<<2) + ii)*256 + j0 + (tn<<2) + jj] =
        __expf(-(qnr[ii] + knc[jj] - 2.0f*d[ii][jj]) * INV_TAU);
}

// ---------------------------------------------------------------------------
// gauss_av
// ---------------------------------------------------------------------------
template<int YMODE, int RQ, int RK, typename TQ, typename TK, typename TV>
__global__ __launch_bounds__(256) void gauss_av(
    const TQ* __restrict__ Q, const TK* __restrict__ Km,
    const TV* __restrict__ V, const float* __restrict__ qn,
    const float* __restrict__ kn, float* __restrict__ Out)
{
  __shared__ float Qs[64][68];
  __shared__ float Kst[64][66];
  __shared__ float Ss[64][68];
  const int bh = blockIdx.x, i0 = blockIdx.y*64;
  const int t = threadIdx.x, tm = t>>4, tn = t&15;
  #pragma unroll
  for (int e=0;e<4;e++){
    int f = e*256 + t; int r = f>>4; int c4 = (f&15)<<2;
    int gi = i0 + r; if (gi > RQ-1) gi = RQ-1;
    *(float4*)&Qs[r][c4] = ld4(Q + (size_t)(bh*RQ + gi)*64 + c4);
  }
  float qnr[4];
  #pragma unroll
  for (int ii=0;ii<4;ii++){ int gi = i0 + (tm<<2) + ii; if (gi > RQ-1) gi = RQ-1; qnr[ii] = qn[bh*RQ + gi]; }
  float acc[4][4] = {};
  for (int j0 = 0; j0 < RK; j0 += 64){
    __syncthreads();
    #pragma unroll
    for (int e=0;e<4;e++){
      int f = e*256 + t; int r = f>>4; int c4 = (f&15)<<2;
      float4 k4 = ld4(Km + (size_t)(bh*RK + j0 + r)*64 + c4);
      Kst[c4+0][r]=k4.x; Kst[c4+1][r]=k4.y; Kst[c4+2][r]=k4.z; Kst[c4+3][r]=k4.w;
    }
    __syncthreads();
    float d[4][4] = {};
    for (int k0=0;k0<64;k0+=4){
      float qv[4][4], kv[4][4];
      #pragma unroll
      for (int ii=0;ii<4;ii++){
        float4 q4 = *(const float4*)&Qs[(tm<<2)+ii][k0];
        qv[ii][0]=q4.x; qv[ii][1]=q4.y; qv[ii][2]=q4.z; qv[ii][3]=q4.w;
      }
      #pragma unroll
      for (int kk=0;kk<4;kk++)
        #pragma unroll
        for (int jj=0;jj<4;jj++)
          kv[kk][jj] = Kst[k0+kk][(tn<<2)+jj];
      #pragma unroll
      for (int ii=0;ii<4;ii++)
        #pragma unroll
        for (int jj=0;jj<4;jj++){
          d[ii][jj] = fmaf(qv[ii][0], kv[0][jj], d[ii][jj]);
          d[ii][jj] = fmaf(qv[ii][1], kv[1][jj], d[ii][jj]);
          d[ii][jj] = fmaf(qv[ii][2], kv[2][jj], d[ii][jj]);
          d[ii][jj] = fmaf(qv[ii][3], kv[3][jj], d[ii][jj]);
        }
    }
    float knc[4];
    #pragma unroll
    for (int jj=0;jj<4;jj++) knc[jj] = kn[bh*RK + j0 + (tn<<2) + jj];
    #pragma unroll
    for (int ii=0;ii<4;ii++)
      #pragma unroll
      for (int jj=0;jj<4;jj++)
        Ss[(tm<<2)+ii][(tn<<2)+jj] = __expf(-(qnr[ii] + knc[jj] - 2.0f*d[ii][jj]) * INV_TAU);
    __syncthreads();
    const TV* Vb = V + (size_t)(bh*RK + j0)*64;
    for (int c0=0;c0<64;c0+=4){
      float sv[4][4], vv[4][4];
      #pragma unroll
      for (int ii=0;ii<4;ii++){
        float4 s4 = *(const float4*)&Ss[(tm<<2)+ii][c0];
        sv[ii][0]=s4.x; sv[ii][1]=s4.y; sv[ii][2]=s4.z; sv[ii][3]=s4.w;
      }
      #pragma unroll
      for (int cc=0;cc<4;cc++){
        float4 v4 = ld4(Vb + (c0+cc)*64 + (tn<<2));
        vv[cc][0]=v4.x; vv[cc][1]=v4.y; vv[cc][2]=v4.z; vv[cc][3]=v4.w;
      }
      #pragma unroll
      for (int ii=0;ii<4;ii++)
        #pragma unroll
        for (int jj=0;jj<4;jj++){
          acc[ii][jj] = fmaf(sv[ii][0], vv[0][jj], acc[ii][jj]);
          acc[ii][jj] = fmaf(sv[ii][1], vv[1][jj], acc[ii][jj]);
          acc[ii][jj] = fmaf(sv[ii][2], vv[2][jj], acc[ii][jj]);
          acc[ii][jj] = fmaf(sv[ii][3], vv[3][jj], acc[ii][jj]);
        }
    }
  }
  #pragma unroll
  for (int ii=0;ii<4;ii++){
    int i = i0 + (tm<<2) + ii;
    if (i < RQ){
      if (YMODE){
        int b = bh / 12, h = bh - b*12;
        float* ob = Out + (size_t)(b*1025 + i)*768 + h*64 + (tn<<2);
        ob[0]=acc[ii][0]; ob[1]=acc[ii][1]; ob[2]=acc[ii][2]; ob[3]=acc[ii][3];
      } else {
        float* ob = Out + (size_t)(bh*RQ + i)*64 + (tn<<2);
        ob[0]=acc[ii][0]; ob[1]=acc[ii][1]; ob[2]=acc[ii][2]; ob[3]=acc[ii][3];
      }
    }
  }
}

// ---------------------------------------------------------------------------
template<typename T>
__global__ __launch_bounds__(256) void rownorm(
    const T* __restrict__ x, float* __restrict__ out, int rows)
{
  int gt = blockIdx.x*256 + threadIdx.x;
  int w = gt >> 6, lane = gt & 63;
  if (w >= rows) return;
  float v = ldf(x + (size_t)w*64 + lane);
  float s = v*v;
  #pragma unroll
  for (int off=32; off>0; off>>=1) s += __shfl_xor(s, off, 64);
  if (lane == 0) out[w] = s;
}

__global__ __launch_bounds__(256) void m2norm(
    const float* __restrict__ M2, float* __restrict__ nrm)
{
  __shared__ float red[256];
  int bh = blockIdx.x, i = threadIdx.x;
  const float* r = M2 + ((size_t)bh*256 + i)*256;
  float s = 0.f;
  for (int j=0;j<256;j++) s += fabsf(r[j]);
  red[i] = s; __syncthreads();
  for (int st=128; st>0; st>>=1){
    if (i < st) red[i] = fmaxf(red[i], red[i+st]);
    __syncthreads();
  }
  if (i == 0) nrm[bh] = red[0];
}

__global__ __launch_bounds__(256) void newton_init(
    const float* __restrict__ M2, const float* __restrict__ nrm, float* __restrict__ inv)
{
  __shared__ float T[64][65];
  int bh = blockIdx.x, i0 = blockIdx.y*64, j0 = blockIdx.z*64;
  float nn = nrm[bh];
  float sc = 1.0f/(nn*nn + 1e-6f);
  const float* Mb = M2 + (size_t)bh*65536;
  float* ob = inv + (size_t)bh*65536;
  int t = threadIdx.x;
  #pragma unroll
  for (int e=0;e<16;e++){ int f=e*256+t; int r=f>>6, c=f&63; T[r][c] = Mb[(i0+r)*256 + j0+c]; }
  __syncthreads();
  #pragma unroll
  for (int e=0;e<16;e++){ int f=e*256+t; int r=f>>6, c=f&63; ob[(j0+r)*256 + i0+c] = T[c][r]*sc; }
}

__global__ __launch_bounds__(256) void diag_fill(u16* out, int n, float val)
{
  int i = blockIdx.x*256 + threadIdx.x;
  if (i < n) out[i] = f2bf(val);
}

// ---------------------------------------------------------------------------
extern "C" void kernel_launch(void* const* d_in, const int* in_sizes, int n_in,
                              void* d_out, int out_size, void* d_ws, size_t ws_size,
                              hipStream_t stream)
{
  char* base = (char*)d_ws;
  size_t off = 0;
  auto A = [&](size_t bytes)->char*{ char* r = base + off; off += (bytes + 255) & ~(size_t)255; return r; };
  int*   flag = (int*)A(256);
  float* XP   = (float*)A((size_t)NBATCH*LM*768*4);     // x_pooled; later KV
  float* QL   = (float*)A((size_t)BH*LM*64*4);          // ql; later Vm
  float* KL   = (float*)A((size_t)BH*LM*64*4);
  char*  M2Y  = A((size_t)MROWS*768*4);                 // M2 (48MB); later y (50.4MB)
  char*  KPV  = A((size_t)MROWS*768*4);                 // kp+vp bf16; Newton temps; later q f32
  float* qn   = (float*)A((size_t)BH*NSEQ*4);
  float* qln  = (float*)A((size_t)BH*LM*4);
  float* kln  = (float*)A((size_t)BH*LM*4);
  float* kpn  = (float*)A((size_t)BH*NP*4);
  float* nrm  = (float*)A(256*4);
  if (ws_size < off){
    diag_fill<<<(out_size+255)/256, 256, 0, stream>>>((u16*)d_out, out_size, (float)(ws_size >> 20));
    return;
  }
  float* M2 = (float*)M2Y;
  float* y  = (float*)M2Y;
  float* KV = XP;
  float* Vm = QL;
  u16*   kp = (u16*)KPV;
  u16*   vp = (u16*)(KPV + (size_t)BH*NP*64*2);
  float* T0 = (float*)KPV;
  float* T1 = T0 + (size_t)64*65536;
  float* T2 = T0 + (size_t)128*65536;
  float* q  = (float*)KPV;

  probe_dtype<<<1, 256, 0, stream>>>((const u16*)d_in[0], flag);

  #define DUAL(kernelcall_f, kernelcall_b) do { kernelcall_f; kernelcall_b; } while(0)
  const float* xf = (const float*)d_in[0]; const u16* xb = (const u16*)d_in[0];
  const float* wf = (const float*)d_in[1]; const u16* wb = (const u16*)d_in[1];
  const float* bf = (const float*)d_in[2]; const u16* bb = (const u16*)d_in[2];
  const float* pwf= (const float*)d_in[3]; const u16* pwb= (const u16*)d_in[3];
  const float* pbf= (const float*)d_in[4]; const u16* pbb= (const u16*)d_in[4];

  // 1. x_pooled
  DUAL((xpool<float><<<(NBATCH*LM*768)/256,256,0,stream>>>(flag,0,xf,XP)),
       (xpool<u16>  <<<(NBATCH*LM*768)/256,256,0,stream>>>(flag,1,xb,XP)));
  // 2. ql, kl
  DUAL((lgemm<float><<<dim3(64,12),256,0,stream>>>(flag,0,XP,wf,bf,0,QL)),
       (lgemm<u16>  <<<dim3(64,12),256,0,stream>>>(flag,1,XP,wb,bb,0,QL)));
  DUAL((lgemm<float><<<dim3(64,12),256,0,stream>>>(flag,0,XP,wf,bf,768,KL)),
       (lgemm<u16>  <<<dim3(64,12),256,0,stream>>>(flag,1,XP,wb,bb,768,KL)));
  // 3. norms + M2
  rownorm<float><<<(BH*LM*64)/256,256,0,stream>>>(QL, qln, BH*LM);
  rownorm<float><<<(BH*LM*64)/256,256,0,stream>>>(KL, kln, BH*LM);
  gauss_m2<<<dim3(BH,4,4),256,0,stream>>>(QL, KL, qln, kln, M2);
  m2norm<<<BH,256,0,stream>>>(M2, nrm);
  // 4. kp, vp
  DUAL((kvgemm<float><<<dim3(256,24),256,0,stream>>>(flag,0,xf,wf,bf,kp,vp)),
       (kvgemm<u16>  <<<dim3(256,24),256,0,stream>>>(flag,1,xb,wb,bb,kp,vp)));
  rownorm<u16><<<(BH*NP*64)/256,256,0,stream>>>(kp, kpn, BH*NP);
  // 5. KV
  gauss_av<0,256,1024,float,u16,u16><<<dim3(BH,4),256,0,stream>>>(QL, kp, vp, qln, kpn, KV);
  // 6. Newton via MFMA split-bf16 (3 groups of 64)
  for (int g = 0; g < 3; ++g){
    const float* M2g = M2 + (size_t)g*64*65536;
    newton_init<<<dim3(64,4,4),256,0,stream>>>(M2g, nrm + g*64, T0);
    float* cur = T0; float* nxt = T2;
    for (int it = 0; it < 6; ++it){
      mgemm<1><<<dim3(64,4,4),256,0,stream>>>(M2g, cur, T1);
      mgemm<0><<<dim3(64,4,4),256,0,stream>>>(cur, T1, nxt);
      float* tt = cur; cur = nxt; nxt = tt;
    }
    bgemm<0,64><<<dim3(64,4,1),256,0,stream>>>(cur, KV + (size_t)g*64*16384,
                                               Vm + (size_t)g*64*16384);
  }
  // 7. q + qn
  DUAL((qgemm<float><<<dim3(257,12),256,0,stream>>>(flag,0,xf,wf,bf,q)),
       (qgemm<u16>  <<<dim3(257,12),256,0,stream>>>(flag,1,xb,wb,bb,q)));
  rownorm<float><<<(BH*NSEQ*64+255)/256*1,256,0,stream>>>(q, qn, BH*NSEQ);
  // 8. y
  gauss_av<1,1025,256,float,float,float><<<dim3(BH,17),256,0,stream>>>(q, KL, Vm, qn, kln, y);
  // 9. out
  DUAL((projgemm<float><<<dim3(257,12),256,0,stream>>>(flag,0,y,pwf,pbf,(float*)d_out)),
       (projgemm<u16>  <<<dim3(257,12),256,0,stream>>>(flag,1,y,pwb,pbb,(u16*)d_out)));
}

// Round 5
// 2346.062 us; speedup vs baseline: 1.3360x; 1.2003x over previous
//
#include <hip/hip_runtime.h>

typedef unsigned short u16;

#define NBATCH 16
#define NHEADS 12
#define BH 192
#define NSEQ 1025
#define NP 1024
#define HD 64
#define LM 256
#define INV_TAU 0.125f
#define MROWS 16400   // NBATCH*NSEQ
#define MT_X 1032     // padded m-tiles for 16400 rows (129 blocks * 8)
#define KB768 24      // 768/32 k-blocks
#define XS_ELE ((size_t)MT_X*KB768*64*8)   // 12,681,216 u16 per (hi or lo)

__device__ __forceinline__ float bf2f(u16 u){
  union { unsigned int i; float f; } x; x.i = ((unsigned int)u)<<16; return x.f;
}
__device__ __forceinline__ u16 f2bf(float f){
  union { float f; unsigned int i; } x; x.f = f;
  unsigned int r = x.i + 0x7fffu + ((x.i >> 16) & 1u);
  return (u16)(r >> 16);
}
__device__ __forceinline__ float ldf(const float* p){ return *p; }
__device__ __forceinline__ float ldf(const u16* p){ return bf2f(*p); }
__device__ __forceinline__ float4 ld4(const float* p){ return *(const float4*)p; }
__device__ __forceinline__ float4 ld4(const u16* p){
  uint2 u = *(const uint2*)p;
  return make_float4(bf2f((u16)u.x), bf2f((u16)(u.x>>16)),
                     bf2f((u16)u.y), bf2f((u16)(u.y>>16)));
}
__device__ __forceinline__ void stf(float* p, float v){ *p = v; }
__device__ __forceinline__ void stf(u16* p, float v){ *p = f2bf(v); }

typedef __attribute__((ext_vector_type(8))) short s8v;
typedef __attribute__((ext_vector_type(4))) float f4v;

// A-pack: lane=(m&15)|(((k>>3)&3)<<4), j=k&7, idx=((mt*KB+kb)*64+lane)*8+j
// B-pack: lane=(n&15)|(((k>>3)&3)<<4), j=k&7, idx=((nt*KB+kb)*64+lane)*8+j

// ---------------------------------------------------------------------------
__global__ __launch_bounds__(256) void probe_dtype(const u16* __restrict__ x, int* flag)
{
  __shared__ int cnt;
  if (threadIdx.x == 0) cnt = 0;
  __syncthreads();
  int c = 0;
  #pragma unroll
  for (int j = 0; j < 8; ++j){
    u16 u = x[2*(threadIdx.x*8 + j)];
    int e = (u >> 7) & 0xFF;
    if (e >= 100 && e <= 140) c++;
  }
  atomicAdd(&cnt, c);
  __syncthreads();
  if (threadIdx.x == 0) *flag = (cnt > 1024) ? 1 : 0;
}

// ---------------------------------------------------------------------------
template<typename TIN>
__global__ __launch_bounds__(256) void cvt_bias(
    const int* __restrict__ flag, int want,
    const TIN* __restrict__ bq_in, const TIN* __restrict__ bp_in,
    float* __restrict__ bq, float* __restrict__ bp)
{
  if (*flag != want) return;
  int i = blockIdx.x*256 + threadIdx.x;
  if (i < 2304) bq[i] = ldf(bq_in + i);
  if (i < 768)  bp[i] = ldf(bp_in + i);
}

// ---------------------------------------------------------------------------
// pack rows-major (rows x 768) fp32/bf16 matrix into hi/lo fragment layout.
// Works for A-pack (x) and B-pack (W) since both use the same index formula.
// ---------------------------------------------------------------------------
template<typename TIN>
__global__ __launch_bounds__(256) void pack_ab(
    const int* __restrict__ flag, int want,
    const TIN* __restrict__ X, int rows_max, int tiles,
    u16* __restrict__ Dh, u16* __restrict__ Dl)
{
  if (*flag != want) return;
  int tid = blockIdx.x*256 + threadIdx.x;
  if (tid >= tiles*KB768*64) return;
  int lane = tid & 63;
  int kb = (tid >> 6) % KB768;
  int mt = tid / (KB768*64);
  int m = mt*16 + (lane & 15); if (m > rows_max-1) m = rows_max-1;
  int k = kb*32 + ((lane>>4) << 3);
  const TIN* src = X + (size_t)m*768 + k;
  float4 a = ld4(src), b = ld4(src + 4);
  float v[8] = {a.x,a.y,a.z,a.w,b.x,b.y,b.z,b.w};
  ushort4 h0,h1,l0,l1;
  u16 h;
  h=f2bf(v[0]); h0.x=h; l0.x=f2bf(v[0]-bf2f(h));
  h=f2bf(v[1]); h0.y=h; l0.y=f2bf(v[1]-bf2f(h));
  h=f2bf(v[2]); h0.z=h; l0.z=f2bf(v[2]-bf2f(h));
  h=f2bf(v[3]); h0.w=h; l0.w=f2bf(v[3]-bf2f(h));
  h=f2bf(v[4]); h1.x=h; l1.x=f2bf(v[4]-bf2f(h));
  h=f2bf(v[5]); h1.y=h; l1.y=f2bf(v[5]-bf2f(h));
  h=f2bf(v[6]); h1.z=h; l1.z=f2bf(v[6]-bf2f(h));
  h=f2bf(v[7]); h1.w=h; l1.w=f2bf(v[7]-bf2f(h));
  size_t o = (size_t)tid*8;
  *(ushort4*)(Dh+o)   = h0; *(ushort4*)(Dh+o+4) = h1;
  *(ushort4*)(Dl+o)   = l0; *(ushort4*)(Dl+o+4) = l1;
}

// ---------------------------------------------------------------------------
// qkv_mfma: C(16400x2304) = x @ qkv_w^T + bias, split-bf16 MFMA.
// grid(129, 36): 8 m-tiles x 4 n-tiles per block. Scatter to q (f32), kp/vp (bf16).
// ---------------------------------------------------------------------------
__global__ __launch_bounds__(256) void qkv_mfma(
    const u16* __restrict__ Xh, const u16* __restrict__ Xl,
    const u16* __restrict__ Wh, const u16* __restrict__ Wl,
    const float* __restrict__ bq,
    float* __restrict__ q, u16* __restrict__ kp, u16* __restrict__ vp)
{
  __shared__ u16 sAh[8*512], sAl[8*512], sBh[4*512], sBl[4*512];
  const int t = threadIdx.x, lane = t & 63, w = t >> 6;
  const int mt0 = blockIdx.x * 8;
  const int by  = blockIdx.y;
  const int nt0 = by * 4;
  const int wr = w >> 1, wc = w & 1;
  f4v acc[4][2];
  #pragma unroll
  for (int a=0;a<4;a++){ acc[a][0]=(f4v){0,0,0,0}; acc[a][1]=(f4v){0,0,0,0}; }
  for (int kb = 0; kb < KB768; ++kb){
    #pragma unroll
    for (int e = 0; e < 6; ++e){
      int cid = e*4 + w;
      const u16* src; u16* dst;
      if (cid < 16){
        int tile = cid >> 1;
        src = ((cid & 1) ? Xl : Xh) + ((size_t)(mt0 + tile)*KB768 + kb)*512 + lane*8;
        dst = ((cid & 1) ? sAl : sAh) + tile*512 + lane*8;
      } else {
        int bc = cid - 16; int tile = bc >> 1;
        src = ((bc & 1) ? Wl : Wh) + ((size_t)(nt0 + tile)*KB768 + kb)*512 + lane*8;
        dst = ((bc & 1) ? sBl : sBh) + tile*512 + lane*8;
      }
      *(uint4*)dst = *(const uint4*)src;
    }
    __syncthreads();
    s8v ah[4], al[4], bh2[2], bl2[2];
    #pragma unroll
    for (int i=0;i<4;i++){
      ah[i] = *(const s8v*)&sAh[(wr*4+i)*512 + lane*8];
      al[i] = *(const s8v*)&sAl[(wr*4+i)*512 + lane*8];
    }
    #pragma unroll
    for (int i=0;i<2;i++){
      bh2[i] = *(const s8v*)&sBh[(wc*2+i)*512 + lane*8];
      bl2[i] = *(const s8v*)&sBl[(wc*2+i)*512 + lane*8];
    }
    #pragma unroll
    for (int mi=0;mi<4;mi++)
      #pragma unroll
      for (int ni=0;ni<2;ni++){
        acc[mi][ni] = __builtin_amdgcn_mfma_f32_16x16x32_bf16(ah[mi], bh2[ni], acc[mi][ni],0,0,0);
        acc[mi][ni] = __builtin_amdgcn_mfma_f32_16x16x32_bf16(al[mi], bh2[ni], acc[mi][ni],0,0,0);
        acc[mi][ni] = __builtin_amdgcn_mfma_f32_16x16x32_bf16(ah[mi], bl2[ni], acc[mi][ni],0,0,0);
      }
    __syncthreads();
  }
  const int which = by / 12, h = by % 12;
  #pragma unroll
  for (int mi=0;mi<4;mi++)
    #pragma unroll
    for (int ni=0;ni<2;ni++){
      int d = (wc*2+ni)*16 + (lane & 15);
      float bias = bq[by*64 + d];
      int mbase = (mt0 + wr*4+mi)*16 + ((lane>>4)<<2);
      #pragma unroll
      for (int r=0;r<4;r++){
        int m = mbase + r;
        if (m >= MROWS) continue;
        float v = acc[mi][ni][r] + bias;
        int b = m / 1025, n = m - b*1025;
        if (which == 0) q[((size_t)(b*12+h)*1025 + n)*64 + d] = v;
        else if (n >= 1){
          size_t idx = ((size_t)(b*12+h)*1024 + (n-1))*64 + d;
          if (which == 1) kp[idx] = f2bf(v); else vp[idx] = f2bf(v);
        }
      }
    }
}

// ---------------------------------------------------------------------------
// proj_mfma: out(16400x768) = Y @ proj_w^T + bias, both operands split hi/lo.
// grid(129, 12). TOUT dual per flag.
// ---------------------------------------------------------------------------
template<typename TOUT>
__global__ __launch_bounds__(256) void proj_mfma(
    const int* __restrict__ flag, int want,
    const u16* __restrict__ Yh, const u16* __restrict__ Yl,
    const u16* __restrict__ Wh, const u16* __restrict__ Wl,
    const float* __restrict__ bp, TOUT* __restrict__ Out)
{
  if (*flag != want) return;
  __shared__ u16 sAh[8*512], sAl[8*512], sBh[4*512], sBl[4*512];
  const int t = threadIdx.x, lane = t & 63, w = t >> 6;
  const int mt0 = blockIdx.x * 8;
  const int by  = blockIdx.y;
  const int nt0 = by * 4;
  const int wr = w >> 1, wc = w & 1;
  f4v acc[4][2];
  #pragma unroll
  for (int a=0;a<4;a++){ acc[a][0]=(f4v){0,0,0,0}; acc[a][1]=(f4v){0,0,0,0}; }
  for (int kb = 0; kb < KB768; ++kb){
    #pragma unroll
    for (int e = 0; e < 6; ++e){
      int cid = e*4 + w;
      const u16* src; u16* dst;
      if (cid < 16){
        int tile = cid >> 1;
        src = ((cid & 1) ? Yl : Yh) + ((size_t)(mt0 + tile)*KB768 + kb)*512 + lane*8;
        dst = ((cid & 1) ? sAl : sAh) + tile*512 + lane*8;
      } else {
        int bc = cid - 16; int tile = bc >> 1;
        src = ((bc & 1) ? Wl : Wh) + ((size_t)(nt0 + tile)*KB768 + kb)*512 + lane*8;
        dst = ((bc & 1) ? sBl : sBh) + tile*512 + lane*8;
      }
      *(uint4*)dst = *(const uint4*)src;
    }
    __syncthreads();
    s8v ah[4], al[4], bh2[2], bl2[2];
    #pragma unroll
    for (int i=0;i<4;i++){
      ah[i] = *(const s8v*)&sAh[(wr*4+i)*512 + lane*8];
      al[i] = *(const s8v*)&sAl[(wr*4+i)*512 + lane*8];
    }
    #pragma unroll
    for (int i=0;i<2;i++){
      bh2[i] = *(const s8v*)&sBh[(wc*2+i)*512 + lane*8];
      bl2[i] = *(const s8v*)&sBl[(wc*2+i)*512 + lane*8];
    }
    #pragma unroll
    for (int mi=0;mi<4;mi++)
      #pragma unroll
      for (int ni=0;ni<2;ni++){
        acc[mi][ni] = __builtin_amdgcn_mfma_f32_16x16x32_bf16(ah[mi], bh2[ni], acc[mi][ni],0,0,0);
        acc[mi][ni] = __builtin_amdgcn_mfma_f32_16x16x32_bf16(al[mi], bh2[ni], acc[mi][ni],0,0,0);
        acc[mi][ni] = __builtin_amdgcn_mfma_f32_16x16x32_bf16(ah[mi], bl2[ni], acc[mi][ni],0,0,0);
      }
    __syncthreads();
  }
  #pragma unroll
  for (int mi=0;mi<4;mi++)
    #pragma unroll
    for (int ni=0;ni<2;ni++){
      int d = (wc*2+ni)*16 + (lane & 15);
      int O = by*64 + d;
      float bias = bp[O];
      int mbase = (mt0 + wr*4+mi)*16 + ((lane>>4)<<2);
      #pragma unroll
      for (int r=0;r<4;r++){
        int m = mbase + r;
        if (m >= MROWS) continue;
        stf(Out + (size_t)m*768 + O, acc[mi][ni][r] + bias);
      }
    }
}

// ---------------------------------------------------------------------------
// Newton packed kernels. Per-head 256x256, K-blocks 8, per-head pack = 65536 u16.
// ---------------------------------------------------------------------------
__global__ __launch_bounds__(256) void pack_newtA(
    const float* __restrict__ S, u16* __restrict__ Dh, u16* __restrict__ Dl)
{
  int tid = blockIdx.x*256 + threadIdx.x;   // 32*16*8*64
  int lane = tid & 63;
  int kb = (tid>>6) & 7;
  int mt = (tid>>9) & 15;
  int hd = tid >> 13;
  int m = mt*16 + (lane&15);
  int k = kb*32 + ((lane>>4)<<3);
  const float* src = S + (size_t)hd*65536 + m*256 + k;
  float4 a = *(const float4*)src, b = *(const float4*)(src+4);
  float v[8] = {a.x,a.y,a.z,a.w,b.x,b.y,b.z,b.w};
  ushort4 h0,h1,l0,l1; u16 h;
  h=f2bf(v[0]); h0.x=h; l0.x=f2bf(v[0]-bf2f(h));
  h=f2bf(v[1]); h0.y=h; l0.y=f2bf(v[1]-bf2f(h));
  h=f2bf(v[2]); h0.z=h; l0.z=f2bf(v[2]-bf2f(h));
  h=f2bf(v[3]); h0.w=h; l0.w=f2bf(v[3]-bf2f(h));
  h=f2bf(v[4]); h1.x=h; l1.x=f2bf(v[4]-bf2f(h));
  h=f2bf(v[5]); h1.y=h; l1.y=f2bf(v[5]-bf2f(h));
  h=f2bf(v[6]); h1.z=h; l1.z=f2bf(v[6]-bf2f(h));
  h=f2bf(v[7]); h1.w=h; l1.w=f2bf(v[7]-bf2f(h));
  size_t o = (size_t)hd*65536 + (size_t)((mt*8+kb)*64+lane)*8;
  *(ushort4*)(Dh+o)   = h0; *(ushort4*)(Dh+o+4) = h1;
  *(ushort4*)(Dl+o)   = l0; *(ushort4*)(Dl+o+4) = l1;
}

__global__ __launch_bounds__(256) void newton_initP(
    const float* __restrict__ M2g, const float* __restrict__ nrmg,
    u16* __restrict__ Ah, u16* __restrict__ Al,
    u16* __restrict__ Bh, u16* __restrict__ Bl)
{
  __shared__ float T[64][65];
  int hd = blockIdx.x, i0 = blockIdx.y*64, j0 = blockIdx.z*64;
  float nn = nrmg[hd];
  float sc = 1.0f/(nn*nn + 1e-6f);
  const float* Mb = M2g + (size_t)hd*65536;
  size_t hs = (size_t)hd*65536;
  int t = threadIdx.x;
  #pragma unroll
  for (int e=0;e<16;e++){ int f=e*256+t; int r=f>>6, c=f&63; T[r][c] = Mb[(i0+r)*256 + j0+c]; }
  __syncthreads();
  #pragma unroll
  for (int e=0;e<16;e++){
    int f=e*256+t; int r=f>>6, c=f&63;
    float v = T[c][r]*sc;           // inv[j0+r][i0+c]
    int row = j0+r, col = i0+c;
    u16 hv = f2bf(v), lv = f2bf(v - bf2f(hv));
    size_t iA = hs + (size_t)(((row>>4)*8 + (col>>5))*64 + ((row&15)|(((col>>3)&3)<<4)))*8 + (col&7);
    Ah[iA]=hv; Al[iA]=lv;
    size_t iB = hs + (size_t)(((col>>4)*8 + (row>>5))*64 + ((col&15)|(((row>>3)&3)<<4)))*8 + (row&7);
    Bh[iB]=hv; Bl[iB]=lv;
  }
}

// MODE1: Ts = 2I - A@B -> B-pack out. MODE0: A@B -> A-pack + B-pack out.
// MODE2: A@B -> fp32 out.
template<int MODE>
__global__ __launch_bounds__(256) void mgemmP(
    const u16* __restrict__ Ah_, const u16* __restrict__ Al_,
    const u16* __restrict__ Bh_, const u16* __restrict__ Bl_,
    u16* __restrict__ oAh, u16* __restrict__ oAl,
    u16* __restrict__ oBh, u16* __restrict__ oBl, float* __restrict__ oF)
{
  __shared__ u16 sAh[2048], sAl[2048], sBh[2048], sBl[2048];
  const int t = threadIdx.x, lane = t & 63, w = t >> 6;
  const int hd = blockIdx.x;
  const int mt0 = blockIdx.y * 4, nt0 = blockIdx.z * 4;
  const size_t hs = (size_t)hd * 65536;
  const int wr = w >> 1, wc = w & 1;
  f4v acc[2][2];
  acc[0][0]=(f4v){0,0,0,0}; acc[0][1]=(f4v){0,0,0,0};
  acc[1][0]=(f4v){0,0,0,0}; acc[1][1]=(f4v){0,0,0,0};
  for (int kb = 0; kb < 8; ++kb){
    #pragma unroll
    for (int e = 0; e < 4; ++e){
      int cid = e*4 + w;
      const u16* src; u16* dst;
      if (cid < 8){
        int tile = cid >> 1;
        src = ((cid & 1) ? Al_ : Ah_) + hs + (size_t)((mt0+tile)*8 + kb)*512 + lane*8;
        dst = ((cid & 1) ? sAl : sAh) + tile*512 + lane*8;
      } else {
        int bc = cid - 8; int tile = bc >> 1;
        src = ((bc & 1) ? Bl_ : Bh_) + hs + (size_t)((nt0+tile)*8 + kb)*512 + lane*8;
        dst = ((bc & 1) ? sBl : sBh) + tile*512 + lane*8;
      }
      *(uint4*)dst = *(const uint4*)src;
    }
    __syncthreads();
    s8v a_h[2], a_l[2], b_h[2], b_l[2];
    #pragma unroll
    for (int i=0;i<2;i++){
      a_h[i] = *(const s8v*)&sAh[(wr*2+i)*512 + lane*8];
      a_l[i] = *(const s8v*)&sAl[(wr*2+i)*512 + lane*8];
      b_h[i] = *(const s8v*)&sBh[(wc*2+i)*512 + lane*8];
      b_l[i] = *(const s8v*)&sBl[(wc*2+i)*512 + lane*8];
    }
    #pragma unroll
    for (int mi=0;mi<2;mi++)
      #pragma unroll
      for (int ni=0;ni<2;ni++){
        acc[mi][ni] = __builtin_amdgcn_mfma_f32_16x16x32_bf16(a_h[mi], b_h[ni], acc[mi][ni],0,0,0);
        acc[mi][ni] = __builtin_amdgcn_mfma_f32_16x16x32_bf16(a_l[mi], b_h[ni], acc[mi][ni],0,0,0);
        acc[mi][ni] = __builtin_amdgcn_mfma_f32_16x16x32_bf16(a_h[mi], b_l[ni], acc[mi][ni],0,0,0);
      }
    __syncthreads();
  }
  #pragma unroll
  for (int mi=0;mi<2;mi++)
    #pragma unroll
    for (int ni=0;ni<2;ni++){
      int col = (nt0 + wc*2+ni)*16 + (lane & 15);
      int rowb = (mt0 + wr*2+mi)*16 + ((lane>>4)<<2);
      #pragma unroll
      for (int r=0;r<4;r++){
        int row = rowb + r;
        float v = acc[mi][ni][r];
        if (MODE == 1) v = ((row==col)?2.0f:0.0f) - v;
        if (MODE == 2){
          oF[hs + (size_t)row*256 + col] = v;
        } else {
          u16 hv = f2bf(v), lv = f2bf(v - bf2f(hv));
          if (MODE == 0){
            size_t iA = hs + (size_t)(((row>>4)*8 + (col>>5))*64 + ((row&15)|(((col>>3)&3)<<4)))*8 + (col&7);
            oAh[iA]=hv; oAl[iA]=lv;
          }
          size_t iB = hs + (size_t)(((col>>4)*8 + (row>>5))*64 + ((col&15)|(((row>>3)&3)<<4)))*8 + (row&7);
          oBh[iB]=hv; oBl[iB]=lv;
        }
      }
    }
}

// ---------------------------------------------------------------------------
// xpool / lgemm (SIMT, landmark path stays fp32-exact)
// ---------------------------------------------------------------------------
template<typename TIN>
__global__ __launch_bounds__(256) void xpool(
    const int* __restrict__ flag, int want,
    const TIN* __restrict__ X, float* __restrict__ XP)
{
  if (*flag != want) return;
  int idx = blockIdx.x*256 + threadIdx.x;
  if (idx >= NBATCH*LM*768) return;
  int c = idx % 768;
  int l = (idx / 768) & 255;
  int b = idx / (768*256);
  int lr = l >> 4, lc = l & 15;
  int p = lr*64 + lc*2;
  const TIN* xb = X + (size_t)b*NSEQ*768;
  XP[idx] = 0.25f*(ldf(xb + (size_t)(p+1)*768 + c) + ldf(xb + (size_t)(p+2)*768 + c)
                 + ldf(xb + (size_t)(p+33)*768 + c) + ldf(xb + (size_t)(p+34)*768 + c));
}

template<typename TIN>
__global__ __launch_bounds__(256) void lgemm(
    const int* __restrict__ flag, int want,
    const float* __restrict__ XP, const TIN* __restrict__ W, const TIN* __restrict__ Bias,
    int ob, float* __restrict__ OutL)
{
  if (*flag != want) return;
  __shared__ float As[16][68];
  __shared__ float Bs[16][68];
  const int t = threadIdx.x;
  const int m0 = blockIdx.x*64, o0 = blockIdx.y*64;
  const int tm = t>>4, tn = t&15;
  const int la_m = t>>2, la_k = (t&3)<<2;
  float acc[4][4] = {};
  const float* ap0 = XP + (size_t)(m0+la_m)*768 + la_k;
  const TIN* bp0 = W + (size_t)(ob+o0+la_m)*768 + la_k;
  for (int k0 = 0; k0 < 768; k0 += 16){
    float4 a4 = *(const float4*)(ap0 + k0);
    float4 b4 = ld4(bp0 + k0);
    As[la_k+0][la_m]=a4.x; As[la_k+1][la_m]=a4.y; As[la_k+2][la_m]=a4.z; As[la_k+3][la_m]=a4.w;
    Bs[la_k+0][la_m]=b4.x; Bs[la_k+1][la_m]=b4.y; Bs[la_k+2][la_m]=b4.z; Bs[la_k+3][la_m]=b4.w;
    __syncthreads();
    #pragma unroll
    for (int kk = 0; kk < 16; ++kk){
      float4 av = *(const float4*)&As[kk][tm<<2];
      float4 bv = *(const float4*)&Bs[kk][tn<<2];
      float ar[4]={av.x,av.y,av.z,av.w}, br[4]={bv.x,bv.y,bv.z,bv.w};
      #pragma unroll
      for (int ii=0;ii<4;ii++)
        #pragma unroll
        for (int jj=0;jj<4;jj++)
          acc[ii][jj] = fmaf(ar[ii], br[jj], acc[ii][jj]);
    }
    __syncthreads();
  }
  const int h = o0 >> 6;
  #pragma unroll
  for (int ii=0;ii<4;ii++){
    int m = m0 + (tm<<2) + ii;
    int b = m >> 8, l = m & 255;
    #pragma unroll
    for (int jj=0;jj<4;jj++){
      int d = (tn<<2) + jj;
      OutL[((size_t)(b*12+h)*256 + l)*64 + d] = acc[ii][jj] + ldf(Bias + ob + o0 + d);
    }
  }
}

// ---------------------------------------------------------------------------
// tierB SIMT kernels (round-4 fallback)
// ---------------------------------------------------------------------------
template<typename TIN>
__global__ __launch_bounds__(256) void kvgemm(
    const int* __restrict__ flag, int want,
    const TIN* __restrict__ X, const TIN* __restrict__ W, const TIN* __restrict__ Bias,
    u16* __restrict__ kp, u16* __restrict__ vp)
{
  if (*flag != want) return;
  __shared__ float As[16][68];
  __shared__ float Bs[16][68];
  const int t = threadIdx.x;
  const int m0 = blockIdx.x*64, o0 = blockIdx.y*64;
  const int tm = t>>4, tn = t&15;
  const int la_m = t>>2, la_k = (t&3)<<2;
  float acc[4][4] = {};
  int ar = m0 + la_m;
  int arb = ar >> 10, arn = ar & 1023;
  const TIN* ap0 = X + (size_t)(arb*1025 + arn + 1)*768 + la_k;
  const TIN* bp0 = W + (size_t)(768 + o0 + la_m)*768 + la_k;
  for (int k0 = 0; k0 < 768; k0 += 16){
    float4 a4 = ld4(ap0 + k0);
    float4 b4 = ld4(bp0 + k0);
    As[la_k+0][la_m]=a4.x; As[la_k+1][la_m]=a4.y; As[la_k+2][la_m]=a4.z; As[la_k+3][la_m]=a4.w;
    Bs[la_k+0][la_m]=b4.x; Bs[la_k+1][la_m]=b4.y; Bs[la_k+2][la_m]=b4.z; Bs[la_k+3][la_m]=b4.w;
    __syncthreads();
    #pragma unroll
    for (int kk = 0; kk < 16; ++kk){
      float4 av = *(const float4*)&As[kk][tm<<2];
      float4 bv = *(const float4*)&Bs[kk][tn<<2];
      float arr[4]={av.x,av.y,av.z,av.w}, brr[4]={bv.x,bv.y,bv.z,bv.w};
      #pragma unroll
      for (int ii=0;ii<4;ii++)
        #pragma unroll
        for (int jj=0;jj<4;jj++)
          acc[ii][jj] = fmaf(arr[ii], brr[jj], acc[ii][jj]);
    }
    __syncthreads();
  }
  const int isv = (o0 >= 768);
  const int h = ((o0 - (isv ? 768 : 0)) >> 6);
  u16* dst = isv ? vp : kp;
  #pragma unroll
  for (int ii=0;ii<4;ii++){
    int m = m0 + (tm<<2) + ii;
    int b = m >> 10, n1 = m & 1023;
    #pragma unroll
    for (int jj=0;jj<4;jj++){
      int d = (tn<<2) + jj;
      dst[((size_t)(b*12+h)*1024 + n1)*64 + d] = f2bf(acc[ii][jj] + ldf(Bias + 768 + o0 + d));
    }
  }
}

template<typename TIN>
__global__ __launch_bounds__(256) void qgemm(
    const int* __restrict__ flag, int want,
    const TIN* __restrict__ X, const TIN* __restrict__ W, const TIN* __restrict__ Bias,
    float* __restrict__ q)
{
  if (*flag != want) return;
  __shared__ float As[16][68];
  __shared__ float Bs[16][68];
  const int t = threadIdx.x;
  const int m0 = blockIdx.x*64, o0 = blockIdx.y*64;
  const int tm = t>>4, tn = t&15;
  const int la_m = t>>2, la_k = (t&3)<<2;
  float acc[4][4] = {};
  int am = m0 + la_m; if (am > MROWS-1) am = MROWS-1;
  const TIN* ap0 = X + (size_t)am*768 + la_k;
  const TIN* bp0 = W + (size_t)(o0+la_m)*768 + la_k;
  for (int k0 = 0; k0 < 768; k0 += 16){
    float4 a4 = ld4(ap0 + k0);
    float4 b4 = ld4(bp0 + k0);
    As[la_k+0][la_m]=a4.x; As[la_k+1][la_m]=a4.y; As[la_k+2][la_m]=a4.z; As[la_k+3][la_m]=a4.w;
    Bs[la_k+0][la_m]=b4.x; Bs[la_k+1][la_m]=b4.y; Bs[la_k+2][la_m]=b4.z; Bs[la_k+3][la_m]=b4.w;
    __syncthreads();
    #pragma unroll
    for (int kk = 0; kk < 16; ++kk){
      float4 av = *(const float4*)&As[kk][tm<<2];
      float4 bv = *(const float4*)&Bs[kk][tn<<2];
      float arr[4]={av.x,av.y,av.z,av.w}, brr[4]={bv.x,bv.y,bv.z,bv.w};
      #pragma unroll
      for (int ii=0;ii<4;ii++)
        #pragma unroll
        for (int jj=0;jj<4;jj++)
          acc[ii][jj] = fmaf(arr[ii], brr[jj], acc[ii][jj]);
    }
    __syncthreads();
  }
  const int h = o0 >> 6;
  #pragma unroll
  for (int ii=0;ii<4;ii++){
    int m = m0 + (tm<<2) + ii;
    if (m >= MROWS) break;
    int b = m / 1025, n = m - b*1025;
    #pragma unroll
    for (int jj=0;jj<4;jj++){
      int d = (tn<<2) + jj;
      q[((size_t)(b*12+h)*1025 + n)*64 + d] = acc[ii][jj] + ldf(Bias + o0 + d);
    }
  }
}

template<typename TIN>
__global__ __launch_bounds__(256) void projgemm(
    const int* __restrict__ flag, int want,
    const float* __restrict__ Y, const TIN* __restrict__ W, const TIN* __restrict__ Bias,
    TIN* __restrict__ Out)
{
  if (*flag != want) return;
  __shared__ float As[16][68];
  __shared__ float Bs[16][68];
  const int t = threadIdx.x;
  const int m0 = blockIdx.x*64, o0 = blockIdx.y*64;
  const int tm = t>>4, tn = t&15;
  const int la_m = t>>2, la_k = (t&3)<<2;
  float acc[4][4] = {};
  int am = m0 + la_m; if (am > MROWS-1) am = MROWS-1;
  const float* ap0 = Y + (size_t)am*768 + la_k;
  const TIN* bp0 = W + (size_t)(o0+la_m)*768 + la_k;
  for (int k0 = 0; k0 < 768; k0 += 16){
    float4 a4 = *(const float4*)(ap0 + k0);
    float4 b4 = ld4(bp0 + k0);
    As[la_k+0][la_m]=a4.x; As[la_k+1][la_m]=a4.y; As[la_k+2][la_m]=a4.z; As[la_k+3][la_m]=a4.w;
    Bs[la_k+0][la_m]=b4.x; Bs[la_k+1][la_m]=b4.y; Bs[la_k+2][la_m]=b4.z; Bs[la_k+3][la_m]=b4.w;
    __syncthreads();
    #pragma unroll
    for (int kk = 0; kk < 16; ++kk){
      float4 av = *(const float4*)&As[kk][tm<<2];
      float4 bv = *(const float4*)&Bs[kk][tn<<2];
      float arr[4]={av.x,av.y,av.z,av.w}, brr[4]={bv.x,bv.y,bv.z,bv.w};
      #pragma unroll
      for (int ii=0;ii<4;ii++)
        #pragma unroll
        for (int jj=0;jj<4;jj++)
          acc[ii][jj] = fmaf(arr[ii], brr[jj], acc[ii][jj]);
    }
    __syncthreads();
  }
  #pragma unroll
  for (int ii=0;ii<4;ii++){
    int m = m0 + (tm<<2) + ii;
    if (m >= MROWS) break;
    #pragma unroll
    for (int jj=0;jj<4;jj++){
      int o = o0 + (tn<<2) + jj;
      stf(Out + (size_t)m*768 + o, acc[ii][jj] + ldf(Bias + o));
    }
  }
}

// round-4 mgemm (tierB)
template<int MODE>
__global__ __launch_bounds__(256) void mgemm(
    const float* __restrict__ A, const float* __restrict__ B, float* __restrict__ C)
{
  __shared__ u16 Ah[4*64*8], Al[4*64*8];
  __shared__ u16 Bh[4*64*8], Bl[4*64*8];
  const int t = threadIdx.x;
  const int bh = blockIdx.x;
  const int i0 = blockIdx.y*64, j0 = blockIdx.z*64;
  const float* Ab = A + (size_t)bh*65536;
  const float* Bb = B + (size_t)bh*65536;
  float* Cb = C + (size_t)bh*65536;
  const int lane = t & 63, wave = t >> 6;
  const int wr = wave >> 1, wc = wave & 1;
  f4v acc[2][2];
  acc[0][0]=(f4v){0,0,0,0}; acc[0][1]=(f4v){0,0,0,0};
  acc[1][0]=(f4v){0,0,0,0}; acc[1][1]=(f4v){0,0,0,0};
  for (int k0 = 0; k0 < 256; k0 += 32){
    #pragma unroll
    for (int e = 0; e < 2; ++e){
      int f = e*256 + t;
      int r = f >> 3, c4 = (f & 7) << 2;
      float4 ga = *(const float4*)(Ab + (size_t)(i0+r)*256 + k0 + c4);
      int tile = r >> 4, m = r & 15, quad = c4 >> 3, jq = c4 & 7;
      int dst = ((tile*64 + quad*16 + m)*8 + jq);
      float va[4] = {ga.x, ga.y, ga.z, ga.w};
      ushort4 h4, l4; u16 h;
      h = f2bf(va[0]); h4.x = h; l4.x = f2bf(va[0]-bf2f(h));
      h = f2bf(va[1]); h4.y = h; l4.y = f2bf(va[1]-bf2f(h));
      h = f2bf(va[2]); h4.z = h; l4.z = f2bf(va[2]-bf2f(h));
      h = f2bf(va[3]); h4.w = h; l4.w = f2bf(va[3]-bf2f(h));
      *(ushort4*)&Ah[dst] = h4;
      *(ushort4*)&Al[dst] = l4;
    }
    #pragma unroll
    for (int e = 0; e < 2; ++e){
      int f = e*256 + t;
      int k = f >> 4, c4 = (f & 15) << 2;
      float4 gb = *(const float4*)(Bb + (size_t)(k0+k)*256 + j0 + c4);
      int quad = k >> 3, j = k & 7;
      float vb[4] = {gb.x, gb.y, gb.z, gb.w};
      #pragma unroll
      for (int s = 0; s < 4; ++s){
        int n = c4 + s;
        int idx = (((n>>4)*64 + quad*16 + (n&15))*8 + j);
        u16 h = f2bf(vb[s]);
        Bh[idx] = h;
        Bl[idx] = f2bf(vb[s] - bf2f(h));
      }
    }
    __syncthreads();
    s8v ah[2], al[2], bhf[2], blf[2];
    #pragma unroll
    for (int rt = 0; rt < 2; ++rt){
      int gt = wr*2 + rt;
      ah[rt] = *(const s8v*)&Ah[(gt*64 + lane)*8];
      al[rt] = *(const s8v*)&Al[(gt*64 + lane)*8];
    }
    #pragma unroll
    for (int ct = 0; ct < 2; ++ct){
      int gt = wc*2 + ct;
      bhf[ct] = *(const s8v*)&Bh[(gt*64 + lane)*8];
      blf[ct] = *(const s8v*)&Bl[(gt*64 + lane)*8];
    }
    #pragma unroll
    for (int rt = 0; rt < 2; ++rt)
      #pragma unroll
      for (int ct = 0; ct < 2; ++ct){
        acc[rt][ct] = __builtin_amdgcn_mfma_f32_16x16x32_bf16(ah[rt], bhf[ct], acc[rt][ct], 0,0,0);
        acc[rt][ct] = __builtin_amdgcn_mfma_f32_16x16x32_bf16(al[rt], bhf[ct], acc[rt][ct], 0,0,0);
        acc[rt][ct] = __builtin_amdgcn_mfma_f32_16x16x32_bf16(ah[rt], blf[ct], acc[rt][ct], 0,0,0);
      }
    __syncthreads();
  }
  #pragma unroll
  for (int rt = 0; rt < 2; ++rt)
    #pragma unroll
    for (int ct = 0; ct < 2; ++ct){
      int col = j0 + (wc*2+ct)*16 + (lane & 15);
      int rbase = i0 + (wr*2+rt)*16 + (lane >> 4)*4;
      #pragma unroll
      for (int r = 0; r < 4; ++r){
        int row = rbase + r;
        float v = acc[rt][ct][r];
        if (MODE == 1) v = ((row==col) ? 2.0f : 0.0f) - v;
        Cb[(size_t)row*256 + col] = v;
      }
    }
}

template<int MODE, int NDIM>
__global__ __launch_bounds__(256) void bgemm(
    const float* __restrict__ A, const float* __restrict__ B, float* __restrict__ C)
{
  __shared__ float As[16][68];
  __shared__ float Bs[16][68];
  const int t = threadIdx.x;
  const int bh = blockIdx.x;
  const int i0 = blockIdx.y*64, j0 = blockIdx.z*64;
  const int tm = t>>4, tn = t&15;
  const float* Ab = A + (size_t)bh*65536;
  const float* Bb = B + (size_t)bh*256*NDIM;
  float* Cb = C + (size_t)bh*256*NDIM;
  const int la_m = t>>2, la_k = (t&3)<<2;
  const int lb_k = t>>4, lb_n = (t&15)<<2;
  float acc[4][4] = {};
  for (int k0 = 0; k0 < 256; k0 += 16){
    float4 a4 = *(const float4*)(Ab + (i0+la_m)*256 + k0 + la_k);
    As[la_k+0][la_m]=a4.x; As[la_k+1][la_m]=a4.y; As[la_k+2][la_m]=a4.z; As[la_k+3][la_m]=a4.w;
    *(float4*)&Bs[lb_k][lb_n] = *(const float4*)(Bb + (k0+lb_k)*NDIM + j0 + lb_n);
    __syncthreads();
    #pragma unroll
    for (int kk = 0; kk < 16; ++kk){
      float4 av = *(const float4*)&As[kk][tm<<2];
      float4 bv = *(const float4*)&Bs[kk][tn<<2];
      float arr[4]={av.x,av.y,av.z,av.w}, brr[4]={bv.x,bv.y,bv.z,bv.w};
      #pragma unroll
      for (int ii=0;ii<4;ii++)
        #pragma unroll
        for (int jj=0;jj<4;jj++)
          acc[ii][jj] = fmaf(arr[ii], brr[jj], acc[ii][jj]);
    }
    __syncthreads();
  }
  #pragma unroll
  for (int ii=0;ii<4;ii++){
    int i = i0 + (tm<<2) + ii;
    #pragma unroll
    for (int jj=0;jj<4;jj++){
      int j = j0 + (tn<<2) + jj;
      float v = acc[ii][jj];
      if (MODE == 1) v = ((i==j) ? 2.0f : 0.0f) - v;
      Cb[i*NDIM + j] = v;
    }
  }
}

// ---------------------------------------------------------------------------
__global__ __launch_bounds__(256) void gauss_m2(
    const float* __restrict__ Q, const float* __restrict__ K,
    const float* __restrict__ qn, const float* __restrict__ kn, float* __restrict__ Out)
{
  __shared__ float Qs[64][68];
  __shared__ float Kst[64][66];
  const int bh = blockIdx.x, i0 = blockIdx.y*64, j0 = blockIdx.z*64;
  const int t = threadIdx.x, tm = t>>4, tn = t&15;
  #pragma unroll
  for (int e=0;e<4;e++){
    int f = e*256 + t; int r = f>>4; int c4 = (f&15)<<2;
    *(float4*)&Qs[r][c4] = *(const float4*)(Q + (size_t)(bh*256 + i0 + r)*64 + c4);
    float4 k4 = *(const float4*)(K + (size_t)(bh*256 + j0 + r)*64 + c4);
    Kst[c4+0][r]=k4.x; Kst[c4+1][r]=k4.y; Kst[c4+2][r]=k4.z; Kst[c4+3][r]=k4.w;
  }
  __syncthreads();
  float d[4][4] = {};
  for (int k0=0;k0<64;k0+=4){
    float qv[4][4], kv[4][4];
    #pragma unroll
    for (int ii=0;ii<4;ii++){
      float4 q4 = *(const float4*)&Qs[(tm<<2)+ii][k0];
      qv[ii][0]=q4.x; qv[ii][1]=q4.y; qv[ii][2]=q4.z; qv[ii][3]=q4.w;
    }
    #pragma unroll
    for (int kk=0;kk<4;kk++)
      #pragma unroll
      for (int jj=0;jj<4;jj++)
        kv[kk][jj] = Kst[k0+kk][(tn<<2)+jj];
    #pragma unroll
    for (int ii=0;ii<4;ii++)
      #pragma unroll
      for (int jj=0;jj<4;jj++){
        d[ii][jj] = fmaf(qv[ii][0], kv[0][jj], d[ii][jj]);
        d[ii][jj] = fmaf(qv[ii][1], kv[1][jj], d[ii][jj]);
        d[ii][jj] = fmaf(qv[ii][2], kv[2][jj], d[ii][jj]);
        d[ii][jj] = fmaf(qv[ii][3], kv[3][jj], d[ii][jj]);
      }
  }
  float qnr[4], knc[4];
  #pragma unroll
  for (int ii=0;ii<4;ii++) qnr[ii] = qn[bh*256 + i0 + (tm<<2) + ii];
  #pragma unroll
  for (int jj=0;jj<4;jj++) knc[jj] = kn[bh*256 + j0 + (tn<<2) + jj];
  #pragma unroll
  for (int ii=0;ii<4;ii++)
    #pragma unroll
    for (int jj=0;jj<4;jj++)
      Out[(size_t)(bh*256 + i0 + (tm<<2) + ii)*256 + j0 + (tn<<2) + jj] =
        __expf(-(qnr[ii] + knc[jj] - 2.0f*d[ii][jj]) * INV_TAU);
}

// ---------------------------------------------------------------------------
// gauss_av. YMODE0: Out (bh,RQ,64) f32; YMODE1: scatter (b,n,768) f32;
// YMODE2: write split hi/lo A-pack layout (Out cast to u16*, lo at +XS_ELE)
// ---------------------------------------------------------------------------
template<int YMODE, int RQ, int RK, typename TQ, typename TK, typename TV>
__global__ __launch_bounds__(256) void gauss_av(
    const TQ* __restrict__ Q, const TK* __restrict__ Km,
    const TV* __restrict__ V, const float* __restrict__ qn,
    const float* __restrict__ kn, float* __restrict__ Out)
{
  __shared__ float Qs[64][68];
  __shared__ float Kst[64][66];
  __shared__ float Ss[64][68];
  const int bh = blockIdx.x, i0 = blockIdx.y*64;
  const int t = threadIdx.x, tm = t>>4, tn = t&15;
  #pragma unroll
  for (int e=0;e<4;e++){
    int f = e*256 + t; int r = f>>4; int c4 = (f&15)<<2;
    int gi = i0 + r; if (gi > RQ-1) gi = RQ-1;
    *(float4*)&Qs[r][c4] = ld4(Q + (size_t)(bh*RQ + gi)*64 + c4);
  }
  float qnr[4];
  #pragma unroll
  for (int ii=0;ii<4;ii++){ int gi = i0 + (tm<<2) + ii; if (gi > RQ-1) gi = RQ-1; qnr[ii] = qn[bh*RQ + gi]; }
  float acc[4][4] = {};
  for (int j0 = 0; j0 < RK; j0 += 64){
    __syncthreads();
    #pragma unroll
    for (int e=0;e<4;e++){
      int f = e*256 + t; int r = f>>4; int c4 = (f&15)<<2;
      float4 k4 = ld4(Km + (size_t)(bh*RK + j0 + r)*64 + c4);
      Kst[c4+0][r]=k4.x; Kst[c4+1][r]=k4.y; Kst[c4+2][r]=k4.z; Kst[c4+3][r]=k4.w;
    }
    __syncthreads();
    float d[4][4] = {};
    for (int k0=0;k0<64;k0+=4){
      float qv[4][4], kv[4][4];
      #pragma unroll
      for (int ii=0;ii<4;ii++){
        float4 q4 = *(const float4*)&Qs[(tm<<2)+ii][k0];
        qv[ii][0]=q4.x; qv[ii][1]=q4.y; qv[ii][2]=q4.z; qv[ii][3]=q4.w;
      }
      #pragma unroll
      for (int kk=0;kk<4;kk++)
        #pragma unroll
        for (int jj=0;jj<4;jj++)
          kv[kk][jj] = Kst[k0+kk][(tn<<2)+jj];
      #pragma unroll
      for (int ii=0;ii<4;ii++)
        #pragma unroll
        for (int jj=0;jj<4;jj++){
          d[ii][jj] = fmaf(qv[ii][0], kv[0][jj], d[ii][jj]);
          d[ii][jj] = fmaf(qv[ii][1], kv[1][jj], d[ii][jj]);
          d[ii][jj] = fmaf(qv[ii][2], kv[2][jj], d[ii][jj]);
          d[ii][jj] = fmaf(qv[ii][3], kv[3][jj], d[ii][jj]);
        }
    }
    float knc[4];
    #pragma unroll
    for (int jj=0;jj<4;jj++) knc[jj] = kn[bh*RK + j0 + (tn<<2) + jj];
    #pragma unroll
    for (int ii=0;ii<4;ii++)
      #pragma unroll
      for (int jj=0;jj<4;jj++)
        Ss[(tm<<2)+ii][(tn<<2)+jj] = __expf(-(qnr[ii] + knc[jj] - 2.0f*d[ii][jj]) * INV_TAU);
    __syncthreads();
    const TV* Vb = V + (size_t)(bh*RK + j0)*64;
    for (int c0=0;c0<64;c0+=4){
      float sv[4][4], vv[4][4];
      #pragma unroll
      for (int ii=0;ii<4;ii++){
        float4 s4 = *(const float4*)&Ss[(tm<<2)+ii][c0];
        sv[ii][0]=s4.x; sv[ii][1]=s4.y; sv[ii][2]=s4.z; sv[ii][3]=s4.w;
      }
      #pragma unroll
      for (int cc=0;cc<4;cc++){
        float4 v4 = ld4(Vb + (c0+cc)*64 + (tn<<2));
        vv[cc][0]=v4.x; vv[cc][1]=v4.y; vv[cc][2]=v4.z; vv[cc][3]=v4.w;
      }
      #pragma unroll
      for (int ii=0;ii<4;ii++)
        #pragma unroll
        for (int jj=0;jj<4;jj++){
          acc[ii][jj] = fmaf(sv[ii][0], vv[0][jj], acc[ii][jj]);
          acc[ii][jj] = fmaf(sv[ii][1], vv[1][jj], acc[ii][jj]);
          acc[ii][jj] = fmaf(sv[ii][2], vv[2][jj], acc[ii][jj]);
          acc[ii][jj] = fmaf(sv[ii][3], vv[3][jj], acc[ii][jj]);
        }
    }
  }
  #pragma unroll
  for (int ii=0;ii<4;ii++){
    int i = i0 + (tm<<2) + ii;
    if (i < RQ){
      if (YMODE == 1){
        int b = bh / 12, h = bh - b*12;
        float* ob = Out + (size_t)(b*1025 + i)*768 + h*64 + (tn<<2);
        ob[0]=acc[ii][0]; ob[1]=acc[ii][1]; ob[2]=acc[ii][2]; ob[3]=acc[ii][3];
      } else if (YMODE == 2){
        int b = bh / 12, h = bh - b*12;
        int ym = b*1025 + i;
        int c = h*64 + (tn<<2);
        int mt = ym >> 4, mrem = ym & 15;
        int kb = c >> 5, q8 = (c >> 3) & 3, j = c & 7;
        int lanep = mrem + (q8 << 4);
        size_t o = ((size_t)(mt*KB768 + kb)*64 + lanep)*8 + j;
        u16* Yh = (u16*)Out;
        u16* Yl = Yh + XS_ELE;
        ushort4 hv, lv; u16 h2;
        h2=f2bf(acc[ii][0]); hv.x=h2; lv.x=f2bf(acc[ii][0]-bf2f(h2));
        h2=f2bf(acc[ii][1]); hv.y=h2; lv.y=f2bf(acc[ii][1]-bf2f(h2));
        h2=f2bf(acc[ii][2]); hv.z=h2; lv.z=f2bf(acc[ii][2]-bf2f(h2));
        h2=f2bf(acc[ii][3]); hv.w=h2; lv.w=f2bf(acc[ii][3]-bf2f(h2));
        *(ushort4*)(Yh + o) = hv;
        *(ushort4*)(Yl + o) = lv;
      } else {
        float* ob = Out + (size_t)(bh*RQ + i)*64 + (tn<<2);
        ob[0]=acc[ii][0]; ob[1]=acc[ii][1]; ob[2]=acc[ii][2]; ob[3]=acc[ii][3];
      }
    }
  }
}

// ---------------------------------------------------------------------------
template<typename T>
__global__ __launch_bounds__(256) void rownorm(
    const T* __restrict__ x, float* __restrict__ out, int rows)
{
  int gt = blockIdx.x*256 + threadIdx.x;
  int w = gt >> 6, lane = gt & 63;
  if (w >= rows) return;
  float v = ldf(x + (size_t)w*64 + lane);
  float s = v*v;
  #pragma unroll
  for (int off=32; off>0; off>>=1) s += __shfl_xor(s, off, 64);
  if (lane == 0) out[w] = s;
}

__global__ __launch_bounds__(256) void m2norm(
    const float* __restrict__ M2, float* __restrict__ nrm)
{
  __shared__ float red[256];
  int bh = blockIdx.x, i = threadIdx.x;
  const float* r = M2 + ((size_t)bh*256 + i)*256;
  float s = 0.f;
  for (int j=0;j<256;j++) s += fabsf(r[j]);
  red[i] = s; __syncthreads();
  for (int st=128; st>0; st>>=1){
    if (i < st) red[i] = fmaxf(red[i], red[i+st]);
    __syncthreads();
  }
  if (i == 0) nrm[bh] = red[0];
}

__global__ __launch_bounds__(256) void newton_init(
    const float* __restrict__ M2, const float* __restrict__ nrm, float* __restrict__ inv)
{
  __shared__ float T[64][65];
  int bh = blockIdx.x, i0 = blockIdx.y*64, j0 = blockIdx.z*64;
  float nn = nrm[bh];
  float sc = 1.0f/(nn*nn + 1e-6f);
  const float* Mb = M2 + (size_t)bh*65536;
  float* ob = inv + (size_t)bh*65536;
  int t = threadIdx.x;
  #pragma unroll
  for (int e=0;e<16;e++){ int f=e*256+t; int r=f>>6, c=f&63; T[r][c] = Mb[(i0+r)*256 + j0+c]; }
  __syncthreads();
  #pragma unroll
  for (int e=0;e<16;e++){ int f=e*256+t; int r=f>>6, c=f&63; ob[(j0+r)*256 + i0+c] = T[c][r]*sc; }
}

__global__ __launch_bounds__(256) void diag_fill(u16* out, int n, float val)
{
  int i = blockIdx.x*256 + threadIdx.x;
  if (i < n) out[i] = f2bf(val);
}

// ---------------------------------------------------------------------------
extern "C" void kernel_launch(void* const* d_in, const int* in_sizes, int n_in,
                              void* d_out, int out_size, void* d_ws, size_t ws_size,
                              hipStream_t stream)
{
  const float* xf = (const float*)d_in[0]; const u16* xb = (const u16*)d_in[0];
  const float* wf = (const float*)d_in[1]; const u16* wb = (const u16*)d_in[1];
  const float* bf = (const float*)d_in[2]; const u16* bb = (const u16*)d_in[2];
  const float* pwf= (const float*)d_in[3]; const u16* pwb= (const u16*)d_in[3];
  const float* pbf= (const float*)d_in[4]; const u16* pbb= (const u16*)d_in[4];
  #define DUAL(kf, kb2) do { kf; kb2; } while(0)

  int* flag = (int*)d_ws;
  probe_dtype<<<1, 256, 0, stream>>>((const u16*)d_in[0], flag);

  // ---------------- tierA plan (MFMA everywhere) ----------------
  {
    char* base = (char*)d_ws;
    size_t off = 256;
    auto A = [&](size_t bytes)->char*{ char* r = base + off; off += (bytes + 255) & ~(size_t)255; return r; };
    u16*  Xh = (u16*)A(XS_ELE*2);       // 25.36MB; -> M2(48MB spans Xh+Xl) -> Y hi/lo
    u16*  Xl = (u16*)A(XS_ELE*2);
    float* q  = (float*)A((size_t)BH*NSEQ*64*4);             // 50.38MB
    char*  KT = A((size_t)6*32*65536*2*2);                   // 50.33MB: kp/vp then 6 newton bufs
    float* XP = (float*)A((size_t)NBATCH*LM*768*4);          // 12.58MB -> KV
    float* QL = (float*)A((size_t)BH*LM*64*4);               // -> Vm
    float* KL = (float*)A((size_t)BH*LM*64*4);
    u16*  Wqh = (u16*)A((size_t)144*KB768*64*8*2);
    u16*  Wql = (u16*)A((size_t)144*KB768*64*8*2);
    u16*  Wph = (u16*)A((size_t)48*KB768*64*8*2);
    u16*  Wpl = (u16*)A((size_t)48*KB768*64*8*2);
    float* curF = (float*)A((size_t)32*65536*4);             // 8.39MB
    float* bq  = (float*)A(2304*4);
    float* bp  = (float*)A(768*4);
    float* qn  = (float*)A((size_t)BH*NSEQ*4);
    float* qln = (float*)A((size_t)BH*LM*4);
    float* kln = (float*)A((size_t)BH*LM*4);
    float* kpn = (float*)A((size_t)BH*NP*4);
    float* nrm = (float*)A(256*4);
    if (ws_size >= off){
      float* M2 = (float*)Xh;                 // 48MB over Xs after qkv
      u16*  Yh = Xh;                          // Y pack over Xs/M2 after Newton
      u16*  Yl = Xh + XS_ELE;
      float* KV = XP;
      float* Vm = QL;
      u16* kp = (u16*)KT;
      u16* vp = (u16*)(KT + (size_t)BH*NP*64*2);
      // newton packed buffers (each 32 heads * 65536 u16 * 2 (hi+lo))
      const size_t PB = (size_t)32*65536;     // u16 elems per (hi or lo) buffer
      u16* nb = (u16*)KT;
      u16 *curAh = nb + 0*2*PB, *curAl = curAh + PB;
      u16 *curBh = nb + 1*2*PB, *curBl = curBh + PB;
      u16 *TsBh  = nb + 2*2*PB, *TsBl  = TsBh  + PB;
      u16 *nxtAh = nb + 3*2*PB, *nxtAl = nxtAh + PB;
      u16 *nxtBh = nb + 4*2*PB, *nxtBl = nxtBh + PB;
      u16 *M2Ah  = nb + 5*2*PB, *M2Al  = M2Ah  + PB;

      DUAL((cvt_bias<float><<<9,256,0,stream>>>(flag,0,bf,pbf,bq,bp)),
           (cvt_bias<u16>  <<<9,256,0,stream>>>(flag,1,bb,pbb,bq,bp)));
      // pack x, qkv_w, proj_w
      DUAL((pack_ab<float><<<MT_X*KB768*64/256,256,0,stream>>>(flag,0,xf,MROWS,MT_X,Xh,Xl)),
           (pack_ab<u16>  <<<MT_X*KB768*64/256,256,0,stream>>>(flag,1,xb,MROWS,MT_X,Xh,Xl)));
      DUAL((pack_ab<float><<<144*KB768*64/256,256,0,stream>>>(flag,0,wf,2304,144,Wqh,Wql)),
           (pack_ab<u16>  <<<144*KB768*64/256,256,0,stream>>>(flag,1,wb,2304,144,Wqh,Wql)));
      DUAL((pack_ab<float><<<48*KB768*64/256,256,0,stream>>>(flag,0,pwf,768,48,Wph,Wpl)),
           (pack_ab<u16>  <<<48*KB768*64/256,256,0,stream>>>(flag,1,pwb,768,48,Wph,Wpl)));
      // q, kp, vp
      qkv_mfma<<<dim3(129,36),256,0,stream>>>(Xh,Xl,Wqh,Wql,bq,q,kp,vp);
      // landmarks (fp32-exact path)
      DUAL((xpool<float><<<(NBATCH*LM*768)/256,256,0,stream>>>(flag,0,xf,XP)),
           (xpool<u16>  <<<(NBATCH*LM*768)/256,256,0,stream>>>(flag,1,xb,XP)));
      DUAL((lgemm<float><<<dim3(64,12),256,0,stream>>>(flag,0,XP,wf,bf,0,QL)),
           (lgemm<u16>  <<<dim3(64,12),256,0,stream>>>(flag,1,XP,wb,bb,0,QL)));
      DUAL((lgemm<float><<<dim3(64,12),256,0,stream>>>(flag,0,XP,wf,bf,768,KL)),
           (lgemm<u16>  <<<dim3(64,12),256,0,stream>>>(flag,1,XP,wb,bb,768,KL)));
      rownorm<float><<<(BH*LM*64)/256,256,0,stream>>>(QL, qln, BH*LM);
      rownorm<float><<<(BH*LM*64)/256,256,0,stream>>>(KL, kln, BH*LM);
      rownorm<float><<<(BH*NSEQ*64)/256,256,0,stream>>>(q, qn, BH*NSEQ);
      rownorm<u16><<<(BH*NP*64)/256,256,0,stream>>>(kp, kpn, BH*NP);
      // M2 over dead Xs region
      gauss_m2<<<dim3(BH,4,4),256,0,stream>>>(QL, KL, qln, kln, M2);
      m2norm<<<BH,256,0,stream>>>(M2, nrm);
      // KV over dead XP
      gauss_av<0,256,1024,float,u16,u16><<<dim3(BH,4),256,0,stream>>>(QL, kp, vp, qln, kpn, KV);
      // Newton: 6 groups of 32 heads, fully packed operand flow
      for (int g = 0; g < 6; ++g){
        const float* M2g = M2 + (size_t)g*32*65536;
        pack_newtA<<<1024,256,0,stream>>>(M2g, M2Ah, M2Al);
        newton_initP<<<dim3(32,4,4),256,0,stream>>>(M2g, nrm+g*32, curAh,curAl,curBh,curBl);
        for (int it = 0; it < 6; ++it){
          mgemmP<1><<<dim3(32,4,4),256,0,stream>>>(M2Ah,M2Al,curBh,curBl,
                                                   nullptr,nullptr,TsBh,TsBl,nullptr);
          if (it < 5){
            mgemmP<0><<<dim3(32,4,4),256,0,stream>>>(curAh,curAl,TsBh,TsBl,
                                                     nxtAh,nxtAl,nxtBh,nxtBl,nullptr);
            u16* t0;
            t0=curAh; curAh=nxtAh; nxtAh=t0;  t0=curAl; curAl=nxtAl; nxtAl=t0;
            t0=curBh; curBh=nxtBh; nxtBh=t0;  t0=curBl; curBl=nxtBl; nxtBl=t0;
          } else {
            mgemmP<2><<<dim3(32,4,4),256,0,stream>>>(curAh,curAl,TsBh,TsBl,
                                                     nullptr,nullptr,nullptr,nullptr,curF);
          }
        }
        bgemm<0,64><<<dim3(32,4,1),256,0,stream>>>(curF, KV + (size_t)g*32*16384,
                                                   Vm + (size_t)g*32*16384);
      }
      // y in split pack layout over dead M2/Xs
      gauss_av<2,1025,256,float,float,float><<<dim3(BH,17),256,0,stream>>>(
          q, KL, Vm, qn, kln, (float*)Yh);
      // out
      DUAL((proj_mfma<float><<<dim3(129,12),256,0,stream>>>(flag,0,Yh,Yl,Wph,Wpl,bp,(float*)d_out)),
           (proj_mfma<u16>  <<<dim3(129,12),256,0,stream>>>(flag,1,Yh,Yl,Wph,Wpl,bp,(u16*)d_out)));
      return;
    }
  }

  // ---------------- tierB plan (round-4 pipeline, ~121MB) ----------------
  {
    char* base = (char*)d_ws;
    size_t off = 256;
    auto A = [&](size_t bytes)->char*{ char* r = base + off; off += (bytes + 255) & ~(size_t)255; return r; };
    float* XP   = (float*)A((size_t)NBATCH*LM*768*4);
    float* QL   = (float*)A((size_t)BH*LM*64*4);
    float* KL   = (float*)A((size_t)BH*LM*64*4);
    char*  M2Y  = A((size_t)MROWS*768*4);
    char*  KPV  = A((size_t)MROWS*768*4);
    float* qn   = (float*)A((size_t)BH*NSEQ*4);
    float* qln  = (float*)A((size_t)BH*LM*4);
    float* kln  = (float*)A((size_t)BH*LM*4);
    float* kpn  = (float*)A((size_t)BH*NP*4);
    float* nrm  = (float*)A(256*4);
    if (ws_size < off){
      diag_fill<<<(out_size+255)/256, 256, 0, stream>>>((u16*)d_out, out_size, (float)(ws_size >> 20));
      return;
    }
    float* M2 = (float*)M2Y;
    float* y  = (float*)M2Y;
    float* KV = XP;
    float* Vm = QL;
    u16*   kp = (u16*)KPV;
    u16*   vp = (u16*)(KPV + (size_t)BH*NP*64*2);
    float* T0 = (float*)KPV;
    float* T1 = T0 + (size_t)64*65536;
    float* T2 = T0 + (size_t)128*65536;
    float* q  = (float*)KPV;

    DUAL((xpool<float><<<(NBATCH*LM*768)/256,256,0,stream>>>(flag,0,xf,XP)),
         (xpool<u16>  <<<(NBATCH*LM*768)/256,256,0,stream>>>(flag,1,xb,XP)));
    DUAL((lgemm<float><<<dim3(64,12),256,0,stream>>>(flag,0,XP,wf,bf,0,QL)),
         (lgemm<u16>  <<<dim3(64,12),256,0,stream>>>(flag,1,XP,wb,bb,0,QL)));
    DUAL((lgemm<float><<<dim3(64,12),256,0,stream>>>(flag,0,XP,wf,bf,768,KL)),
         (lgemm<u16>  <<<dim3(64,12),256,0,stream>>>(flag,1,XP,wb,bb,768,KL)));
    rownorm<float><<<(BH*LM*64)/256,256,0,stream>>>(QL, qln, BH*LM);
    rownorm<float><<<(BH*LM*64)/256,256,0,stream>>>(KL, kln, BH*LM);
    gauss_m2<<<dim3(BH,4,4),256,0,stream>>>(QL, KL, qln, kln, M2);
    m2norm<<<BH,256,0,stream>>>(M2, nrm);
    DUAL((kvgemm<float><<<dim3(256,24),256,0,stream>>>(flag,0,xf,wf,bf,kp,vp)),
         (kvgemm<u16>  <<<dim3(256,24),256,0,stream>>>(flag,1,xb,wb,bb,kp,vp)));
    rownorm<u16><<<(BH*NP*64)/256,256,0,stream>>>(kp, kpn, BH*NP);
    gauss_av<0,256,1024,float,u16,u16><<<dim3(BH,4),256,0,stream>>>(QL, kp, vp, qln, kpn, KV);
    for (int g = 0; g < 3; ++g){
      const float* M2g = M2 + (size_t)g*64*65536;
      newton_init<<<dim3(64,4,4),256,0,stream>>>(M2g, nrm + g*64, T0);
      float* cur = T0; float* nxt = T2;
      for (int it = 0; it < 6; ++it){
        mgemm<1><<<dim3(64,4,4),256,0,stream>>>(M2g, cur, T1);
        mgemm<0><<<dim3(64,4,4),256,0,stream>>>(cur, T1, nxt);
        float* tt = cur; cur = nxt; nxt = tt;
      }
      bgemm<0,64><<<dim3(64,4,1),256,0,stream>>>(cur, KV + (size_t)g*64*16384,
                                                 Vm + (size_t)g*64*16384);
    }
    DUAL((qgemm<float><<<dim3(257,12),256,0,stream>>>(flag,0,xf,wf,bf,q)),
         (qgemm<u16>  <<<dim3(257,12),256,0,stream>>>(flag,1,xb,wb,bb,q)));
    rownorm<float><<<(BH*NSEQ*64)/256,256,0,stream>>>(q, qn, BH*NSEQ);
    gauss_av<1,1025,256,float,float,float><<<dim3(BH,17),256,0,stream>>>(q, KL, Vm, qn, kln, y);
    DUAL((projgemm<float><<<dim3(257,12),256,0,stream>>>(flag,0,y,pwf,pbf,(float*)d_out)),
         (projgemm<u16>  <<<dim3(257,12),256,0,stream>>>(flag,1,y,pwb,pbb,(u16*)d_out)));
  }
}

// Round 6
// 1983.676 us; speedup vs baseline: 1.5800x; 1.1827x over previous
//
#include <hip/hip_runtime.h>

typedef unsigned short u16;

#define NBATCH 16
#define NHEADS 12
#define BH 192
#define NSEQ 1025
#define NP 1024
#define HD 64
#define LM 256
#define INV_TAU 0.125f
#define MROWS 16400   // NBATCH*NSEQ
#define MT_X 1032     // padded m-tiles for 16400 rows (129 blocks * 8)
#define KB768 24      // 768/32 k-blocks
#define XS_ELE ((size_t)MT_X*KB768*64*8)   // u16 elems per (hi or lo) x/y pack

__device__ __forceinline__ float bf2f(u16 u){
  union { unsigned int i; float f; } x; x.i = ((unsigned int)u)<<16; return x.f;
}
__device__ __forceinline__ u16 f2bf(float f){
  union { float f; unsigned int i; } x; x.f = f;
  unsigned int r = x.i + 0x7fffu + ((x.i >> 16) & 1u);
  return (u16)(r >> 16);
}
__device__ __forceinline__ float ldf(const float* p){ return *p; }
__device__ __forceinline__ float ldf(const u16* p){ return bf2f(*p); }
__device__ __forceinline__ float4 ld4(const float* p){ return *(const float4*)p; }
__device__ __forceinline__ float4 ld4(const u16* p){
  uint2 u = *(const uint2*)p;
  return make_float4(bf2f((u16)u.x), bf2f((u16)(u.x>>16)),
                     bf2f((u16)u.y), bf2f((u16)(u.y>>16)));
}
__device__ __forceinline__ void stf(float* p, float v){ *p = v; }
__device__ __forceinline__ void stf(u16* p, float v){ *p = f2bf(v); }

typedef __attribute__((ext_vector_type(8))) short s8v;
typedef __attribute__((ext_vector_type(4))) float f4v;

// A-pack: element (m,k): lane=(m&15)|(((k>>3)&3)<<4), j=k&7, tile (mt, kb) mt-major
// B-pack: element (n,k): lane=(n&15)|(((k>>3)&3)<<4), j=k&7

// ---------------------------------------------------------------------------
__global__ __launch_bounds__(256) void probe_dtype(const u16* __restrict__ x, int* flag)
{
  __shared__ int cnt;
  if (threadIdx.x == 0) cnt = 0;
  __syncthreads();
  int c = 0;
  #pragma unroll
  for (int j = 0; j < 8; ++j){
    u16 u = x[2*(threadIdx.x*8 + j)];
    int e = (u >> 7) & 0xFF;
    if (e >= 100 && e <= 140) c++;
  }
  atomicAdd(&cnt, c);
  __syncthreads();
  if (threadIdx.x == 0) *flag = (cnt > 1024) ? 1 : 0;
}

template<typename TIN>
__global__ __launch_bounds__(256) void cvt_bias(
    const int* __restrict__ flag, int want,
    const TIN* __restrict__ bq_in, const TIN* __restrict__ bp_in,
    float* __restrict__ bq, float* __restrict__ bp)
{
  if (*flag != want) return;
  int i = blockIdx.x*256 + threadIdx.x;
  if (i < 2304) bq[i] = ldf(bq_in + i);
  if (i < 768)  bp[i] = ldf(bp_in + i);
}

// ---------------------------------------------------------------------------
// pack rows-major (rows x 768) matrix into hi/lo A/B fragment pack layout
// ---------------------------------------------------------------------------
template<typename TIN>
__global__ __launch_bounds__(256) void pack_ab(
    const int* __restrict__ flag, int want,
    const TIN* __restrict__ X, int rows_max, int tiles,
    u16* __restrict__ Dh, u16* __restrict__ Dl)
{
  if (*flag != want) return;
  int tid = blockIdx.x*256 + threadIdx.x;
  if (tid >= tiles*KB768*64) return;
  int lane = tid & 63;
  int kb = (tid >> 6) % KB768;
  int mt = tid / (KB768*64);
  int m = mt*16 + (lane & 15); if (m > rows_max-1) m = rows_max-1;
  int k = kb*32 + ((lane>>4) << 3);
  const TIN* src = X + (size_t)m*768 + k;
  float4 a = ld4(src), b = ld4(src + 4);
  float v[8] = {a.x,a.y,a.z,a.w,b.x,b.y,b.z,b.w};
  ushort4 h0,h1,l0,l1;
  u16 h;
  h=f2bf(v[0]); h0.x=h; l0.x=f2bf(v[0]-bf2f(h));
  h=f2bf(v[1]); h0.y=h; l0.y=f2bf(v[1]-bf2f(h));
  h=f2bf(v[2]); h0.z=h; l0.z=f2bf(v[2]-bf2f(h));
  h=f2bf(v[3]); h0.w=h; l0.w=f2bf(v[3]-bf2f(h));
  h=f2bf(v[4]); h1.x=h; l1.x=f2bf(v[4]-bf2f(h));
  h=f2bf(v[5]); h1.y=h; l1.y=f2bf(v[5]-bf2f(h));
  h=f2bf(v[6]); h1.z=h; l1.z=f2bf(v[6]-bf2f(h));
  h=f2bf(v[7]); h1.w=h; l1.w=f2bf(v[7]-bf2f(h));
  size_t o = (size_t)tid*8;
  *(ushort4*)(Dh+o)   = h0; *(ushort4*)(Dh+o+4) = h1;
  *(ushort4*)(Dl+o)   = l0; *(ushort4*)(Dl+o+4) = l1;
}

// ---------------------------------------------------------------------------
// qkv_mfma: grid(36,129): bx = 64-col block of 2304, by*8 = m-tile strip.
// Writes q fp32 row-major; kp in K-B-pack (n=krow,k=d); vp in V-B-pack (n=d,k=krow).
// ---------------------------------------------------------------------------
__global__ __launch_bounds__(256) void qkv_mfma(
    const u16* __restrict__ Xh, const u16* __restrict__ Xl,
    const u16* __restrict__ Wh, const u16* __restrict__ Wl,
    const float* __restrict__ bq,
    float* __restrict__ q, u16* __restrict__ kp, u16* __restrict__ vp)
{
  __shared__ u16 sAh[8*512], sAl[8*512], sBh[4*512], sBl[4*512];
  const int t = threadIdx.x, lane = t & 63, w = t >> 6;
  const int by  = blockIdx.x;           // n-block (0..35) — fast dim for L2 reuse of X
  const int mt0 = blockIdx.y * 8;
  const int nt0 = by * 4;
  const int wr = w >> 1, wc = w & 1;
  f4v acc[4][2];
  #pragma unroll
  for (int a=0;a<4;a++){ acc[a][0]=(f4v){0,0,0,0}; acc[a][1]=(f4v){0,0,0,0}; }
  for (int kb = 0; kb < KB768; ++kb){
    #pragma unroll
    for (int e = 0; e < 6; ++e){
      int cid = e*4 + w;
      const u16* src; u16* dst;
      if (cid < 16){
        int tile = cid >> 1;
        src = ((cid & 1) ? Xl : Xh) + ((size_t)(mt0 + tile)*KB768 + kb)*512 + lane*8;
        dst = ((cid & 1) ? sAl : sAh) + tile*512 + lane*8;
      } else {
        int bc = cid - 16; int tile = bc >> 1;
        src = ((bc & 1) ? Wl : Wh) + ((size_t)(nt0 + tile)*KB768 + kb)*512 + lane*8;
        dst = ((bc & 1) ? sBl : sBh) + tile*512 + lane*8;
      }
      *(uint4*)dst = *(const uint4*)src;
    }
    __syncthreads();
    s8v ah[4], al[4], bh2[2], bl2[2];
    #pragma unroll
    for (int i=0;i<4;i++){
      ah[i] = *(const s8v*)&sAh[(wr*4+i)*512 + lane*8];
      al[i] = *(const s8v*)&sAl[(wr*4+i)*512 + lane*8];
    }
    #pragma unroll
    for (int i=0;i<2;i++){
      bh2[i] = *(const s8v*)&sBh[(wc*2+i)*512 + lane*8];
      bl2[i] = *(const s8v*)&sBl[(wc*2+i)*512 + lane*8];
    }
    #pragma unroll
    for (int mi=0;mi<4;mi++)
      #pragma unroll
      for (int ni=0;ni<2;ni++){
        acc[mi][ni] = __builtin_amdgcn_mfma_f32_16x16x32_bf16(ah[mi], bh2[ni], acc[mi][ni],0,0,0);
        acc[mi][ni] = __builtin_amdgcn_mfma_f32_16x16x32_bf16(al[mi], bh2[ni], acc[mi][ni],0,0,0);
        acc[mi][ni] = __builtin_amdgcn_mfma_f32_16x16x32_bf16(ah[mi], bl2[ni], acc[mi][ni],0,0,0);
      }
    __syncthreads();
  }
  const int which = by / 12, h = by % 12;
  #pragma unroll
  for (int mi=0;mi<4;mi++)
    #pragma unroll
    for (int ni=0;ni<2;ni++){
      int d = (wc*2+ni)*16 + (lane & 15);
      float bias = bq[by*64 + d];
      int mbase = (mt0 + wr*4+mi)*16 + ((lane>>4)<<2);
      #pragma unroll
      for (int r=0;r<4;r++){
        int m = mbase + r;
        if (m >= MROWS) continue;
        float v = acc[mi][ni][r] + bias;
        int b = m / 1025, n = m - b*1025;
        int bh = b*12 + h;
        if (which == 0) q[((size_t)bh*1025 + n)*64 + d] = v;
        else if (n >= 1){
          int kr = n - 1;
          if (which == 1){
            size_t idx = (size_t)bh*65536 +
              (size_t)((((kr>>4)*2 + (d>>5))*64) + ((kr&15)|(((d>>3)&3)<<4)))*8 + (d&7);
            kp[idx] = f2bf(v);
          } else {
            size_t idx = (size_t)bh*65536 +
              (size_t)((((kr>>5)*4 + (d>>4))*64) + ((d&15)|(((kr>>3)&3)<<4)))*8 + (kr&7);
            vp[idx] = f2bf(v);
          }
        }
      }
    }
}

// ---------------------------------------------------------------------------
// proj_mfma: grid(12,129), Y pack + W pack, out per flag dtype
// ---------------------------------------------------------------------------
template<typename TOUT>
__global__ __launch_bounds__(256) void proj_mfma(
    const int* __restrict__ flag, int want,
    const u16* __restrict__ Yh, const u16* __restrict__ Yl,
    const u16* __restrict__ Wh, const u16* __restrict__ Wl,
    const float* __restrict__ bp, TOUT* __restrict__ Out)
{
  if (*flag != want) return;
  __shared__ u16 sAh[8*512], sAl[8*512], sBh[4*512], sBl[4*512];
  const int t = threadIdx.x, lane = t & 63, w = t >> 6;
  const int by  = blockIdx.x;
  const int mt0 = blockIdx.y * 8;
  const int nt0 = by * 4;
  const int wr = w >> 1, wc = w & 1;
  f4v acc[4][2];
  #pragma unroll
  for (int a=0;a<4;a++){ acc[a][0]=(f4v){0,0,0,0}; acc[a][1]=(f4v){0,0,0,0}; }
  for (int kb = 0; kb < KB768; ++kb){
    #pragma unroll
    for (int e = 0; e < 6; ++e){
      int cid = e*4 + w;
      const u16* src; u16* dst;
      if (cid < 16){
        int tile = cid >> 1;
        src = ((cid & 1) ? Yl : Yh) + ((size_t)(mt0 + tile)*KB768 + kb)*512 + lane*8;
        dst = ((cid & 1) ? sAl : sAh) + tile*512 + lane*8;
      } else {
        int bc = cid - 16; int tile = bc >> 1;
        src = ((bc & 1) ? Wl : Wh) + ((size_t)(nt0 + tile)*KB768 + kb)*512 + lane*8;
        dst = ((bc & 1) ? sBl : sBh) + tile*512 + lane*8;
      }
      *(uint4*)dst = *(const uint4*)src;
    }
    __syncthreads();
    s8v ah[4], al[4], bh2[2], bl2[2];
    #pragma unroll
    for (int i=0;i<4;i++){
      ah[i] = *(const s8v*)&sAh[(wr*4+i)*512 + lane*8];
      al[i] = *(const s8v*)&sAl[(wr*4+i)*512 + lane*8];
    }
    #pragma unroll
    for (int i=0;i<2;i++){
      bh2[i] = *(const s8v*)&sBh[(wc*2+i)*512 + lane*8];
      bl2[i] = *(const s8v*)&sBl[(wc*2+i)*512 + lane*8];
    }
    #pragma unroll
    for (int mi=0;mi<4;mi++)
      #pragma unroll
      for (int ni=0;ni<2;ni++){
        acc[mi][ni] = __builtin_amdgcn_mfma_f32_16x16x32_bf16(ah[mi], bh2[ni], acc[mi][ni],0,0,0);
        acc[mi][ni] = __builtin_amdgcn_mfma_f32_16x16x32_bf16(al[mi], bh2[ni], acc[mi][ni],0,0,0);
        acc[mi][ni] = __builtin_amdgcn_mfma_f32_16x16x32_bf16(ah[mi], bl2[ni], acc[mi][ni],0,0,0);
      }
    __syncthreads();
  }
  #pragma unroll
  for (int mi=0;mi<4;mi++)
    #pragma unroll
    for (int ni=0;ni<2;ni++){
      int d = (wc*2+ni)*16 + (lane & 15);
      int O = by*64 + d;
      float bias = bp[O];
      int mbase = (mt0 + wr*4+mi)*16 + ((lane>>4)<<2);
      #pragma unroll
      for (int r=0;r<4;r++){
        int m = mbase + r;
        if (m >= MROWS) continue;
        stf(Out + (size_t)m*768 + O, acc[mi][ni][r] + bias);
      }
    }
}

// ---------------------------------------------------------------------------
// Newton packed kernels (unchanged from round 5)
// ---------------------------------------------------------------------------
__global__ __launch_bounds__(256) void pack_newtA(
    const float* __restrict__ S, u16* __restrict__ Dh, u16* __restrict__ Dl)
{
  int tid = blockIdx.x*256 + threadIdx.x;
  int lane = tid & 63;
  int kb = (tid>>6) & 7;
  int mt = (tid>>9) & 15;
  int hd = tid >> 13;
  int m = mt*16 + (lane&15);
  int k = kb*32 + ((lane>>4)<<3);
  const float* src = S + (size_t)hd*65536 + m*256 + k;
  float4 a = *(const float4*)src, b = *(const float4*)(src+4);
  float v[8] = {a.x,a.y,a.z,a.w,b.x,b.y,b.z,b.w};
  ushort4 h0,h1,l0,l1; u16 h;
  h=f2bf(v[0]); h0.x=h; l0.x=f2bf(v[0]-bf2f(h));
  h=f2bf(v[1]); h0.y=h; l0.y=f2bf(v[1]-bf2f(h));
  h=f2bf(v[2]); h0.z=h; l0.z=f2bf(v[2]-bf2f(h));
  h=f2bf(v[3]); h0.w=h; l0.w=f2bf(v[3]-bf2f(h));
  h=f2bf(v[4]); h1.x=h; l1.x=f2bf(v[4]-bf2f(h));
  h=f2bf(v[5]); h1.y=h; l1.y=f2bf(v[5]-bf2f(h));
  h=f2bf(v[6]); h1.z=h; l1.z=f2bf(v[6]-bf2f(h));
  h=f2bf(v[7]); h1.w=h; l1.w=f2bf(v[7]-bf2f(h));
  size_t o = (size_t)hd*65536 + (size_t)((mt*8+kb)*64+lane)*8;
  *(ushort4*)(Dh+o)   = h0; *(ushort4*)(Dh+o+4) = h1;
  *(ushort4*)(Dl+o)   = l0; *(ushort4*)(Dl+o+4) = l1;
}

__global__ __launch_bounds__(256) void newton_initP(
    const float* __restrict__ M2g, const float* __restrict__ nrmg,
    u16* __restrict__ Ah, u16* __restrict__ Al,
    u16* __restrict__ Bh, u16* __restrict__ Bl)
{
  __shared__ float T[64][65];
  int hd = blockIdx.x, i0 = blockIdx.y*64, j0 = blockIdx.z*64;
  float nn = nrmg[hd];
  float sc = 1.0f/(nn*nn + 1e-6f);
  const float* Mb = M2g + (size_t)hd*65536;
  size_t hs = (size_t)hd*65536;
  int t = threadIdx.x;
  #pragma unroll
  for (int e=0;e<16;e++){ int f=e*256+t; int r=f>>6, c=f&63; T[r][c] = Mb[(i0+r)*256 + j0+c]; }
  __syncthreads();
  #pragma unroll
  for (int e=0;e<16;e++){
    int f=e*256+t; int r=f>>6, c=f&63;
    float v = T[c][r]*sc;
    int row = j0+r, col = i0+c;
    u16 hv = f2bf(v), lv = f2bf(v - bf2f(hv));
    size_t iA = hs + (size_t)(((row>>4)*8 + (col>>5))*64 + ((row&15)|(((col>>3)&3)<<4)))*8 + (col&7);
    Ah[iA]=hv; Al[iA]=lv;
    size_t iB = hs + (size_t)(((col>>4)*8 + (row>>5))*64 + ((col&15)|(((row>>3)&3)<<4)))*8 + (row&7);
    Bh[iB]=hv; Bl[iB]=lv;
  }
}

template<int MODE>
__global__ __launch_bounds__(256) void mgemmP(
    const u16* __restrict__ Ah_, const u16* __restrict__ Al_,
    const u16* __restrict__ Bh_, const u16* __restrict__ Bl_,
    u16* __restrict__ oAh, u16* __restrict__ oAl,
    u16* __restrict__ oBh, u16* __restrict__ oBl, float* __restrict__ oF)
{
  __shared__ u16 sAh[2048], sAl[2048], sBh[2048], sBl[2048];
  const int t = threadIdx.x, lane = t & 63, w = t >> 6;
  const int hd = blockIdx.x;
  const int mt0 = blockIdx.y * 4, nt0 = blockIdx.z * 4;
  const size_t hs = (size_t)hd * 65536;
  const int wr = w >> 1, wc = w & 1;
  f4v acc[2][2];
  acc[0][0]=(f4v){0,0,0,0}; acc[0][1]=(f4v){0,0,0,0};
  acc[1][0]=(f4v){0,0,0,0}; acc[1][1]=(f4v){0,0,0,0};
  for (int kb = 0; kb < 8; ++kb){
    #pragma unroll
    for (int e = 0; e < 4; ++e){
      int cid = e*4 + w;
      const u16* src; u16* dst;
      if (cid < 8){
        int tile = cid >> 1;
        src = ((cid & 1) ? Al_ : Ah_) + hs + (size_t)((mt0+tile)*8 + kb)*512 + lane*8;
        dst = ((cid & 1) ? sAl : sAh) + tile*512 + lane*8;
      } else {
        int bc = cid - 8; int tile = bc >> 1;
        src = ((bc & 1) ? Bl_ : Bh_) + hs + (size_t)((nt0+tile)*8 + kb)*512 + lane*8;
        dst = ((bc & 1) ? sBl : sBh) + tile*512 + lane*8;
      }
      *(uint4*)dst = *(const uint4*)src;
    }
    __syncthreads();
    s8v a_h[2], a_l[2], b_h[2], b_l[2];
    #pragma unroll
    for (int i=0;i<2;i++){
      a_h[i] = *(const s8v*)&sAh[(wr*2+i)*512 + lane*8];
      a_l[i] = *(const s8v*)&sAl[(wr*2+i)*512 + lane*8];
      b_h[i] = *(const s8v*)&sBh[(wc*2+i)*512 + lane*8];
      b_l[i] = *(const s8v*)&sBl[(wc*2+i)*512 + lane*8];
    }
    #pragma unroll
    for (int mi=0;mi<2;mi++)
      #pragma unroll
      for (int ni=0;ni<2;ni++){
        acc[mi][ni] = __builtin_amdgcn_mfma_f32_16x16x32_bf16(a_h[mi], b_h[ni], acc[mi][ni],0,0,0);
        acc[mi][ni] = __builtin_amdgcn_mfma_f32_16x16x32_bf16(a_l[mi], b_h[ni], acc[mi][ni],0,0,0);
        acc[mi][ni] = __builtin_amdgcn_mfma_f32_16x16x32_bf16(a_h[mi], b_l[ni], acc[mi][ni],0,0,0);
      }
    __syncthreads();
  }
  #pragma unroll
  for (int mi=0;mi<2;mi++)
    #pragma unroll
    for (int ni=0;ni<2;ni++){
      int col = (nt0 + wc*2+ni)*16 + (lane & 15);
      int rowb = (mt0 + wr*2+mi)*16 + ((lane>>4)<<2);
      #pragma unroll
      for (int r=0;r<4;r++){
        int row = rowb + r;
        float v = acc[mi][ni][r];
        if (MODE == 1) v = ((row==col)?2.0f:0.0f) - v;
        if (MODE == 2){
          oF[hs + (size_t)row*256 + col] = v;
        } else {
          u16 hv = f2bf(v), lv = f2bf(v - bf2f(hv));
          if (MODE == 0){
            size_t iA = hs + (size_t)(((row>>4)*8 + (col>>5))*64 + ((row&15)|(((col>>3)&3)<<4)))*8 + (col&7);
            oAh[iA]=hv; oAl[iA]=lv;
          }
          size_t iB = hs + (size_t)(((col>>4)*8 + (row>>5))*64 + ((col&15)|(((row>>3)&3)<<4)))*8 + (row&7);
          oBh[iB]=hv; oBl[iB]=lv;
        }
      }
    }
}

// ---------------------------------------------------------------------------
// xpool / lgemm / gauss_m2 (SIMT fp32-exact landmark path, unchanged)
// ---------------------------------------------------------------------------
template<typename TIN>
__global__ __launch_bounds__(256) void xpool(
    const int* __restrict__ flag, int want,
    const TIN* __restrict__ X, float* __restrict__ XP)
{
  if (*flag != want) return;
  int idx = blockIdx.x*256 + threadIdx.x;
  if (idx >= NBATCH*LM*768) return;
  int c = idx % 768;
  int l = (idx / 768) & 255;
  int b = idx / (768*256);
  int lr = l >> 4, lc = l & 15;
  int p = lr*64 + lc*2;
  const TIN* xb = X + (size_t)b*NSEQ*768;
  XP[idx] = 0.25f*(ldf(xb + (size_t)(p+1)*768 + c) + ldf(xb + (size_t)(p+2)*768 + c)
                 + ldf(xb + (size_t)(p+33)*768 + c) + ldf(xb + (size_t)(p+34)*768 + c));
}

template<typename TIN>
__global__ __launch_bounds__(256) void lgemm(
    const int* __restrict__ flag, int want,
    const float* __restrict__ XP, const TIN* __restrict__ W, const TIN* __restrict__ Bias,
    int ob, float* __restrict__ OutL)
{
  if (*flag != want) return;
  __shared__ float As[16][68];
  __shared__ float Bs[16][68];
  const int t = threadIdx.x;
  const int m0 = blockIdx.x*64, o0 = blockIdx.y*64;
  const int tm = t>>4, tn = t&15;
  const int la_m = t>>2, la_k = (t&3)<<2;
  float acc[4][4] = {};
  const float* ap0 = XP + (size_t)(m0+la_m)*768 + la_k;
  const TIN* bp0 = W + (size_t)(ob+o0+la_m)*768 + la_k;
  for (int k0 = 0; k0 < 768; k0 += 16){
    float4 a4 = *(const float4*)(ap0 + k0);
    float4 b4 = ld4(bp0 + k0);
    As[la_k+0][la_m]=a4.x; As[la_k+1][la_m]=a4.y; As[la_k+2][la_m]=a4.z; As[la_k+3][la_m]=a4.w;
    Bs[la_k+0][la_m]=b4.x; Bs[la_k+1][la_m]=b4.y; Bs[la_k+2][la_m]=b4.z; Bs[la_k+3][la_m]=b4.w;
    __syncthreads();
    #pragma unroll
    for (int kk = 0; kk < 16; ++kk){
      float4 av = *(const float4*)&As[kk][tm<<2];
      float4 bv = *(const float4*)&Bs[kk][tn<<2];
      float ar[4]={av.x,av.y,av.z,av.w}, br[4]={bv.x,bv.y,bv.z,bv.w};
      #pragma unroll
      for (int ii=0;ii<4;ii++)
        #pragma unroll
        for (int jj=0;jj<4;jj++)
          acc[ii][jj] = fmaf(ar[ii], br[jj], acc[ii][jj]);
    }
    __syncthreads();
  }
  const int h = o0 >> 6;
  #pragma unroll
  for (int ii=0;ii<4;ii++){
    int m = m0 + (tm<<2) + ii;
    int b = m >> 8, l = m & 255;
    #pragma unroll
    for (int jj=0;jj<4;jj++){
      int d = (tn<<2) + jj;
      OutL[((size_t)(b*12+h)*256 + l)*64 + d] = acc[ii][jj] + ldf(Bias + ob + o0 + d);
    }
  }
}

__global__ __launch_bounds__(256) void gauss_m2(
    const float* __restrict__ Q, const float* __restrict__ K,
    const float* __restrict__ qn, const float* __restrict__ kn, float* __restrict__ Out)
{
  __shared__ float Qs[64][68];
  __shared__ float Kst[64][66];
  const int bh = blockIdx.x, i0 = blockIdx.y*64, j0 = blockIdx.z*64;
  const int t = threadIdx.x, tm = t>>4, tn = t&15;
  #pragma unroll
  for (int e=0;e<4;e++){
    int f = e*256 + t; int r = f>>4; int c4 = (f&15)<<2;
    *(float4*)&Qs[r][c4] = *(const float4*)(Q + (size_t)(bh*256 + i0 + r)*64 + c4);
    float4 k4 = *(const float4*)(K + (size_t)(bh*256 + j0 + r)*64 + c4);
    Kst[c4+0][r]=k4.x; Kst[c4+1][r]=k4.y; Kst[c4+2][r]=k4.z; Kst[c4+3][r]=k4.w;
  }
  __syncthreads();
  float d[4][4] = {};
  for (int k0=0;k0<64;k0+=4){
    float qv[4][4], kv[4][4];
    #pragma unroll
    for (int ii=0;ii<4;ii++){
      float4 q4 = *(const float4*)&Qs[(tm<<2)+ii][k0];
      qv[ii][0]=q4.x; qv[ii][1]=q4.y; qv[ii][2]=q4.z; qv[ii][3]=q4.w;
    }
    #pragma unroll
    for (int kk=0;kk<4;kk++)
      #pragma unroll
      for (int jj=0;jj<4;jj++)
        kv[kk][jj] = Kst[k0+kk][(tn<<2)+jj];
    #pragma unroll
    for (int ii=0;ii<4;ii++)
      #pragma unroll
      for (int jj=0;jj<4;jj++){
        d[ii][jj] = fmaf(qv[ii][0], kv[0][jj], d[ii][jj]);
        d[ii][jj] = fmaf(qv[ii][1], kv[1][jj], d[ii][jj]);
        d[ii][jj] = fmaf(qv[ii][2], kv[2][jj], d[ii][jj]);
        d[ii][jj] = fmaf(qv[ii][3], kv[3][jj], d[ii][jj]);
      }
  }
  float qnr[4], knc[4];
  #pragma unroll
  for (int ii=0;ii<4;ii++) qnr[ii] = qn[bh*256 + i0 + (tm<<2) + ii];
  #pragma unroll
  for (int jj=0;jj<4;jj++) knc[jj] = kn[bh*256 + j0 + (tn<<2) + jj];
  #pragma unroll
  for (int ii=0;ii<4;ii++)
    #pragma unroll
    for (int jj=0;jj<4;jj++)
      Out[(size_t)(bh*256 + i0 + (tm<<2) + ii)*256 + j0 + (tn<<2) + jj] =
        __expf(-(qnr[ii] + knc[jj] - 2.0f*d[ii][jj]) * INV_TAU);
}

// ---------------------------------------------------------------------------
// bgemm tail: C[bh](256x64) = A(256x256 f32) @ B(256x64 f32)
// ---------------------------------------------------------------------------
template<int MODE, int NDIM>
__global__ __launch_bounds__(256) void bgemm(
    const float* __restrict__ A, const float* __restrict__ B, float* __restrict__ C)
{
  __shared__ float As[16][68];
  __shared__ float Bs[16][68];
  const int t = threadIdx.x;
  const int bh = blockIdx.x;
  const int i0 = blockIdx.y*64, j0 = blockIdx.z*64;
  const int tm = t>>4, tn = t&15;
  const float* Ab = A + (size_t)bh*65536;
  const float* Bb = B + (size_t)bh*256*NDIM;
  float* Cb = C + (size_t)bh*256*NDIM;
  const int la_m = t>>2, la_k = (t&3)<<2;
  const int lb_k = t>>4, lb_n = (t&15)<<2;
  float acc[4][4] = {};
  for (int k0 = 0; k0 < 256; k0 += 16){
    float4 a4 = *(const float4*)(Ab + (i0+la_m)*256 + k0 + la_k);
    As[la_k+0][la_m]=a4.x; As[la_k+1][la_m]=a4.y; As[la_k+2][la_m]=a4.z; As[la_k+3][la_m]=a4.w;
    *(float4*)&Bs[lb_k][lb_n] = *(const float4*)(Bb + (k0+lb_k)*NDIM + j0 + lb_n);
    __syncthreads();
    #pragma unroll
    for (int kk = 0; kk < 16; ++kk){
      float4 av = *(const float4*)&As[kk][tm<<2];
      float4 bv = *(const float4*)&Bs[kk][tn<<2];
      float arr[4]={av.x,av.y,av.z,av.w}, brr[4]={bv.x,bv.y,bv.z,bv.w};
      #pragma unroll
      for (int ii=0;ii<4;ii++)
        #pragma unroll
        for (int jj=0;jj<4;jj++)
          acc[ii][jj] = fmaf(arr[ii], brr[jj], acc[ii][jj]);
    }
    __syncthreads();
  }
  #pragma unroll
  for (int ii=0;ii<4;ii++){
    int i = i0 + (tm<<2) + ii;
    #pragma unroll
    for (int jj=0;jj<4;jj++){
      int j = j0 + (tn<<2) + jj;
      float v = acc[ii][jj];
      if (MODE == 1) v = ((i==j) ? 2.0f : 0.0f) - v;
      Cb[i*NDIM + j] = v;
    }
  }
}

// ---------------------------------------------------------------------------
// gauss_av_m: MFMA flash-style  Out = exp(-(qn+kn-2 Q K^T)/tau) @ V
// Q fp32 row-major (split in-kernel). K,V pre-packed B-frag u16 (hi[,lo]).
// YMODE 0: Out f32 (bh,RQ,64). YMODE 2: Out = y A-pack hi/lo (u16, lo at +XS_ELE)
// ---------------------------------------------------------------------------
template<int YMODE, int RQ, int RK, int KSPLIT, int VSPLIT>
__global__ __launch_bounds__(256) void gauss_av_m(
    const float* __restrict__ Q,
    const u16* __restrict__ Kh, const u16* __restrict__ Kl,
    const u16* __restrict__ Vh, const u16* __restrict__ Vl,
    const float* __restrict__ qn, const float* __restrict__ kn,
    float* __restrict__ Out)
{
  __shared__ u16 Ph[4096], Pl[4096];
  const int bh = blockIdx.x, i0 = blockIdx.y*64;
  const int t = threadIdx.x, lane = t&63, w = t>>6, wr = w>>1, wc = w&1;
  const size_t kbase = (size_t)bh*RK*64;
  // Q A-frags hi/lo for wave's 2 m-tiles
  s8v qfh[2][2], qfl[2][2];
  #pragma unroll
  for (int mi=0;mi<2;mi++){
    int row = i0 + (wr*2+mi)*16 + (lane&15);
    if (row > RQ-1) row = RQ-1;
    const float* src = Q + ((size_t)bh*RQ + row)*64 + ((lane>>4)<<3);
    #pragma unroll
    for (int kb=0;kb<2;kb++){
      float4 a = *(const float4*)(src + kb*32);
      float4 b = *(const float4*)(src + kb*32 + 4);
      float v[8]={a.x,a.y,a.z,a.w,b.x,b.y,b.z,b.w};
      union { s8v v8; u16 u[8]; } H, L;
      #pragma unroll
      for (int j=0;j<8;j++){ u16 hh=f2bf(v[j]); H.u[j]=hh; L.u[j]=f2bf(v[j]-bf2f(hh)); }
      qfh[mi][kb]=H.v8; qfl[mi][kb]=L.v8;
    }
  }
  float qnr[2][4];
  #pragma unroll
  for (int mi=0;mi<2;mi++)
    #pragma unroll
    for (int rr=0;rr<4;rr++){
      int row = i0 + (wr*2+mi)*16 + ((lane>>4)<<2) + rr;
      if (row > RQ-1) row = RQ-1;
      qnr[mi][rr] = qn[(size_t)bh*RQ + row];
    }
  f4v oacc[2][2];
  oacc[0][0]=(f4v){0,0,0,0}; oacc[0][1]=(f4v){0,0,0,0};
  oacc[1][0]=(f4v){0,0,0,0}; oacc[1][1]=(f4v){0,0,0,0};

  for (int j0 = 0; j0 < RK; j0 += 64){
    // ---- S = Q K^T for this 64-col chunk
    s8v kfh[2][2], kfl[2][2];
    #pragma unroll
    for (int ci=0;ci<2;ci++){
      int ntg = (j0>>4) + wc*2 + ci;
      #pragma unroll
      for (int kb=0;kb<2;kb++){
        size_t a = kbase + (size_t)((ntg*2+kb)*64 + lane)*8;
        kfh[ci][kb] = *(const s8v*)(Kh + a);
        if (KSPLIT) kfl[ci][kb] = *(const s8v*)(Kl + a);
      }
    }
    f4v sacc[2][2];
    sacc[0][0]=(f4v){0,0,0,0}; sacc[0][1]=(f4v){0,0,0,0};
    sacc[1][0]=(f4v){0,0,0,0}; sacc[1][1]=(f4v){0,0,0,0};
    #pragma unroll
    for (int mi=0;mi<2;mi++)
      #pragma unroll
      for (int ci=0;ci<2;ci++)
        #pragma unroll
        for (int kb=0;kb<2;kb++){
          sacc[mi][ci] = __builtin_amdgcn_mfma_f32_16x16x32_bf16(qfh[mi][kb], kfh[ci][kb], sacc[mi][ci],0,0,0);
          sacc[mi][ci] = __builtin_amdgcn_mfma_f32_16x16x32_bf16(qfl[mi][kb], kfh[ci][kb], sacc[mi][ci],0,0,0);
          if (KSPLIT)
            sacc[mi][ci] = __builtin_amdgcn_mfma_f32_16x16x32_bf16(qfh[mi][kb], kfl[ci][kb], sacc[mi][ci],0,0,0);
        }
    // ---- exp -> P (hi/lo) into LDS A-pack
    float knc[2];
    #pragma unroll
    for (int ci=0;ci<2;ci++)
      knc[ci] = kn[(size_t)bh*RK + j0 + (wc*2+ci)*16 + (lane&15)];
    #pragma unroll
    for (int mi=0;mi<2;mi++)
      #pragma unroll
      for (int ci=0;ci<2;ci++){
        int cl = (wc*2+ci)*16 + (lane&15);
        #pragma unroll
        for (int rr=0;rr<4;rr++){
          int rl = (wr*2+mi)*16 + ((lane>>4)<<2) + rr;
          float p = __expf(-(qnr[mi][rr] + knc[ci] - 2.0f*sacc[mi][ci][rr]) * INV_TAU);
          int ad = (((rl>>4)*2 + (cl>>5))*64 + ((rl&15)|(((cl>>3)&3)<<4)))*8 + (cl&7);
          u16 hh = f2bf(p);
          Ph[ad] = hh; Pl[ad] = f2bf(p - bf2f(hh));
        }
      }
    __syncthreads();
    // ---- O += P @ V
    s8v pfh[2][2], pfl[2][2];
    #pragma unroll
    for (int mi=0;mi<2;mi++)
      #pragma unroll
      for (int kb=0;kb<2;kb++){
        int ad = (((wr*2+mi)*2 + kb)*64 + lane)*8;
        pfh[mi][kb] = *(const s8v*)&Ph[ad];
        pfl[mi][kb] = *(const s8v*)&Pl[ad];
      }
    s8v vfh[2][2], vfl[2][2];
    #pragma unroll
    for (int ni=0;ni<2;ni++){
      int nt = wc*2 + ni;
      #pragma unroll
      for (int kb=0;kb<2;kb++){
        int kbg = (j0>>5) + kb;
        size_t a = kbase + (size_t)((kbg*4 + nt)*64 + lane)*8;
        vfh[ni][kb] = *(const s8v*)(Vh + a);
        if (VSPLIT) vfl[ni][kb] = *(const s8v*)(Vl + a);
      }
    }
    #pragma unroll
    for (int mi=0;mi<2;mi++)
      #pragma unroll
      for (int ni=0;ni<2;ni++)
        #pragma unroll
        for (int kb=0;kb<2;kb++){
          oacc[mi][ni] = __builtin_amdgcn_mfma_f32_16x16x32_bf16(pfh[mi][kb], vfh[ni][kb], oacc[mi][ni],0,0,0);
          oacc[mi][ni] = __builtin_amdgcn_mfma_f32_16x16x32_bf16(pfl[mi][kb], vfh[ni][kb], oacc[mi][ni],0,0,0);
          if (VSPLIT)
            oacc[mi][ni] = __builtin_amdgcn_mfma_f32_16x16x32_bf16(pfh[mi][kb], vfl[ni][kb], oacc[mi][ni],0,0,0);
        }
    __syncthreads();
  }
  // ---- epilogue
  #pragma unroll
  for (int mi=0;mi<2;mi++)
    #pragma unroll
    for (int ni=0;ni<2;ni++){
      int d = (wc*2+ni)*16 + (lane&15);
      #pragma unroll
      for (int rr=0;rr<4;rr++){
        int i = i0 + (wr*2+mi)*16 + ((lane>>4)<<2) + rr;
        if (i >= RQ) continue;
        float v = oacc[mi][ni][rr];
        if (YMODE == 0){
          Out[((size_t)bh*RQ + i)*64 + d] = v;
        } else {
          int b = bh/12, h = bh - b*12;
          int ym = b*1025 + i;
          int c = h*64 + d;
          size_t idx = ((size_t)((ym>>4)*KB768 + (c>>5))*64 + ((ym&15)|(((c>>3)&3)<<4)))*8 + (c&7);
          u16* Yh = (u16*)Out; u16* Yl = Yh + XS_ELE;
          u16 hh = f2bf(v);
          Yh[idx] = hh; Yl[idx] = f2bf(v - bf2f(hh));
        }
      }
    }
}

// ---------------------------------------------------------------------------
// pack KL (fp32 row-major) -> hi/lo K-B-pack (n=krow, k=d), RK=256
// ---------------------------------------------------------------------------
__global__ __launch_bounds__(256) void pack_bKL(
    const float* __restrict__ KL, u16* __restrict__ Dh, u16* __restrict__ Dl)
{
  int tid = blockIdx.x*256 + threadIdx.x;   // BH*2048
  int bh = tid >> 11, rem = tid & 2047;
  int lane = rem & 63, kb = (rem>>6)&1, ntg = rem>>7;
  int krow = ntg*16 + (lane&15);
  int d0 = kb*32 + ((lane>>4)<<3);
  const float* src = KL + ((size_t)bh*256 + krow)*64 + d0;
  float4 a = *(const float4*)src, b = *(const float4*)(src+4);
  float v[8] = {a.x,a.y,a.z,a.w,b.x,b.y,b.z,b.w};
  ushort4 h0,h1,l0,l1; u16 h;
  h=f2bf(v[0]); h0.x=h; l0.x=f2bf(v[0]-bf2f(h));
  h=f2bf(v[1]); h0.y=h; l0.y=f2bf(v[1]-bf2f(h));
  h=f2bf(v[2]); h0.z=h; l0.z=f2bf(v[2]-bf2f(h));
  h=f2bf(v[3]); h0.w=h; l0.w=f2bf(v[3]-bf2f(h));
  h=f2bf(v[4]); h1.x=h; l1.x=f2bf(v[4]-bf2f(h));
  h=f2bf(v[5]); h1.y=h; l1.y=f2bf(v[5]-bf2f(h));
  h=f2bf(v[6]); h1.z=h; l1.z=f2bf(v[6]-bf2f(h));
  h=f2bf(v[7]); h1.w=h; l1.w=f2bf(v[7]-bf2f(h));
  size_t o = (size_t)tid*8;
  *(ushort4*)(Dh+o)   = h0; *(ushort4*)(Dh+o+4) = h1;
  *(ushort4*)(Dl+o)   = l0; *(ushort4*)(Dl+o+4) = l1;
}

// pack Vm (fp32 row-major) -> hi/lo V-B-pack (n=d, k=krow), RK=256
__global__ __launch_bounds__(256) void pack_bVm(
    const float* __restrict__ Vm, u16* __restrict__ Dh, u16* __restrict__ Dl)
{
  int tid = blockIdx.x*256 + threadIdx.x;   // BH*2048
  int bh = tid >> 11, rem = tid & 2047;
  int lane = rem & 63, nt = (rem>>6)&3, kbg = rem>>8;
  int d = nt*16 + (lane&15);
  int kr0 = kbg*32 + ((lane>>4)<<3);
  float v[8];
  #pragma unroll
  for (int j=0;j<8;j++) v[j] = Vm[((size_t)bh*256 + kr0 + j)*64 + d];
  size_t o = (size_t)tid*8;
  #pragma unroll
  for (int j=0;j<8;j++){
    u16 h = f2bf(v[j]);
    Dh[o+j] = h; Dl[o+j] = f2bf(v[j]-bf2f(h));
  }
}

// ---------------------------------------------------------------------------
template<typename T>
__global__ __launch_bounds__(256) void rownorm(
    const T* __restrict__ x, float* __restrict__ out, int rows)
{
  int gt = blockIdx.x*256 + threadIdx.x;
  int w = gt >> 6, lane = gt & 63;
  if (w >= rows) return;
  float v = ldf(x + (size_t)w*64 + lane);
  float s = v*v;
  #pragma unroll
  for (int off=32; off>0; off>>=1) s += __shfl_xor(s, off, 64);
  if (lane == 0) out[w] = s;
}

// row norms of kp stored in K-B-pack layout
__global__ __launch_bounds__(256) void rownorm_kpack(
    const u16* __restrict__ Kp, float* __restrict__ out)
{
  int gt = blockIdx.x*256 + threadIdx.x;
  int wv = gt >> 6, d = gt & 63;
  if (wv >= BH*NP) return;
  int bh = wv >> 10, kr = wv & 1023;
  size_t a = (size_t)bh*65536 +
    (size_t)((((kr>>4)*2 + (d>>5))*64) + ((kr&15)|(((d>>3)&3)<<4)))*8 + (d&7);
  float v = bf2f(Kp[a]);
  float s = v*v;
  #pragma unroll
  for (int off=32; off>0; off>>=1) s += __shfl_xor(s, off, 64);
  if (d == 0) out[wv] = s;
}

__global__ __launch_bounds__(256) void m2norm(
    const float* __restrict__ M2, float* __restrict__ nrm)
{
  __shared__ float red[256];
  int bh = blockIdx.x, i = threadIdx.x;
  const float* r = M2 + ((size_t)bh*256 + i)*256;
  float s = 0.f;
  for (int j=0;j<256;j++) s += fabsf(r[j]);
  red[i] = s; __syncthreads();
  for (int st=128; st>0; st>>=1){
    if (i < st) red[i] = fmaxf(red[i], red[i+st]);
    __syncthreads();
  }
  if (i == 0) nrm[bh] = red[0];
}

__global__ __launch_bounds__(256) void diag_fill(u16* out, int n, float val)
{
  int i = blockIdx.x*256 + threadIdx.x;
  if (i < n) out[i] = f2bf(val);
}

// ---------------------------------------------------------------------------
extern "C" void kernel_launch(void* const* d_in, const int* in_sizes, int n_in,
                              void* d_out, int out_size, void* d_ws, size_t ws_size,
                              hipStream_t stream)
{
  const float* xf = (const float*)d_in[0]; const u16* xb = (const u16*)d_in[0];
  const float* wf = (const float*)d_in[1]; const u16* wb = (const u16*)d_in[1];
  const float* bf = (const float*)d_in[2]; const u16* bb = (const u16*)d_in[2];
  const float* pwf= (const float*)d_in[3]; const u16* pwb= (const u16*)d_in[3];
  const float* pbf= (const float*)d_in[4]; const u16* pbb= (const u16*)d_in[4];
  #define DUAL(kf, kb2) do { kf; kb2; } while(0)

  int* flag = (int*)d_ws;

  char* base = (char*)d_ws;
  size_t off = 256;
  auto A = [&](size_t bytes)->char*{ char* r = base + off; off += (bytes + 255) & ~(size_t)255; return r; };
  u16*  Xh = (u16*)A(XS_ELE*2);       // 25.4MB; -> M2(48MB spans Xh+Xl) -> Y hi/lo
  u16*  Xl = (u16*)A(XS_ELE*2);
  float* q  = (float*)A((size_t)BH*NSEQ*64*4);             // 50.4MB
  char*  KT = A((size_t)6*32*65536*2*2);                   // 50.3MB: Kpack+Vpack, then Newton bufs
  float* XP = (float*)A((size_t)NBATCH*LM*768*4);          // 12.6MB -> KV -> KLpack
  float* QL = (float*)A((size_t)BH*LM*64*4);               // -> Vm
  float* KL = (float*)A((size_t)BH*LM*64*4);               // -> VmPack
  u16*  Wqh = (u16*)A((size_t)144*KB768*64*8*2);
  u16*  Wql = (u16*)A((size_t)144*KB768*64*8*2);
  u16*  Wph = (u16*)A((size_t)48*KB768*64*8*2);
  u16*  Wpl = (u16*)A((size_t)48*KB768*64*8*2);
  float* curF = (float*)A((size_t)32*65536*4);             // 8.4MB
  float* bq  = (float*)A(2304*4);
  float* bp  = (float*)A(768*4);
  float* qn  = (float*)A((size_t)BH*NSEQ*4);
  float* qln = (float*)A((size_t)BH*LM*4);
  float* kln = (float*)A((size_t)BH*LM*4);
  float* kpn = (float*)A((size_t)BH*NP*4);
  float* nrm = (float*)A(256*4);
  if (ws_size < off){
    diag_fill<<<(out_size+255)/256, 256, 0, stream>>>((u16*)d_out, out_size, (float)(ws_size >> 20));
    return;
  }
  float* M2 = (float*)Xh;
  u16*  Yh = Xh;
  u16*  Yl = Xh + XS_ELE;
  float* KV = XP;
  float* Vm = QL;
  u16*  Kp = (u16*)KT;                          // 192*65536 u16
  u16*  Vp = (u16*)KT + (size_t)192*65536;
  u16*  KLh = (u16*)XP;                         // over dead KV (post-Newton)
  u16*  KLl = KLh + (size_t)BH*16384;
  u16*  Vmh = (u16*)KL;                         // over dead KL (post-pack_bKL)
  u16*  Vml = Vmh + (size_t)BH*16384;
  const size_t PB = (size_t)32*65536;
  u16* nb = (u16*)KT;
  u16 *curAh = nb + 0*2*PB, *curAl = curAh + PB;
  u16 *curBh = nb + 1*2*PB, *curBl = curBh + PB;
  u16 *TsBh  = nb + 2*2*PB, *TsBl  = TsBh  + PB;
  u16 *nxtAh = nb + 3*2*PB, *nxtAl = nxtAh + PB;
  u16 *nxtBh = nb + 4*2*PB, *nxtBl = nxtBh + PB;
  u16 *M2Ah  = nb + 5*2*PB, *M2Al  = M2Ah  + PB;

  probe_dtype<<<1, 256, 0, stream>>>((const u16*)d_in[0], flag);
  DUAL((cvt_bias<float><<<9,256,0,stream>>>(flag,0,bf,pbf,bq,bp)),
       (cvt_bias<u16>  <<<9,256,0,stream>>>(flag,1,bb,pbb,bq,bp)));
  // pack x, qkv_w, proj_w
  DUAL((pack_ab<float><<<MT_X*KB768*64/256,256,0,stream>>>(flag,0,xf,MROWS,MT_X,Xh,Xl)),
       (pack_ab<u16>  <<<MT_X*KB768*64/256,256,0,stream>>>(flag,1,xb,MROWS,MT_X,Xh,Xl)));
  DUAL((pack_ab<float><<<144*KB768*64/256,256,0,stream>>>(flag,0,wf,2304,144,Wqh,Wql)),
       (pack_ab<u16>  <<<144*KB768*64/256,256,0,stream>>>(flag,1,wb,2304,144,Wqh,Wql)));
  DUAL((pack_ab<float><<<48*KB768*64/256,256,0,stream>>>(flag,0,pwf,768,48,Wph,Wpl)),
       (pack_ab<u16>  <<<48*KB768*64/256,256,0,stream>>>(flag,1,pwb,768,48,Wph,Wpl)));
  // q (row-major) + kp/vp (B-pack layouts)
  qkv_mfma<<<dim3(36,129),256,0,stream>>>(Xh,Xl,Wqh,Wql,bq,q,Kp,Vp);
  // landmarks (fp32-exact)
  DUAL((xpool<float><<<(NBATCH*LM*768)/256,256,0,stream>>>(flag,0,xf,XP)),
       (xpool<u16>  <<<(NBATCH*LM*768)/256,256,0,stream>>>(flag,1,xb,XP)));
  DUAL((lgemm<float><<<dim3(64,12),256,0,stream>>>(flag,0,XP,wf,bf,0,QL)),
       (lgemm<u16>  <<<dim3(64,12),256,0,stream>>>(flag,1,XP,wb,bb,0,QL)));
  DUAL((lgemm<float><<<dim3(64,12),256,0,stream>>>(flag,0,XP,wf,bf,768,KL)),
       (lgemm<u16>  <<<dim3(64,12),256,0,stream>>>(flag,1,XP,wb,bb,768,KL)));
  // norms
  rownorm<float><<<(BH*LM*64)/256,256,0,stream>>>(QL, qln, BH*LM);
  rownorm<float><<<(BH*LM*64)/256,256,0,stream>>>(KL, kln, BH*LM);
  rownorm<float><<<(BH*NSEQ*64)/256,256,0,stream>>>(q, qn, BH*NSEQ);
  rownorm_kpack<<<(BH*NP*64)/256,256,0,stream>>>(Kp, kpn);
  // M2 (over dead X packs)
  gauss_m2<<<dim3(BH,4,4),256,0,stream>>>(QL, KL, qln, kln, M2);
  m2norm<<<BH,256,0,stream>>>(M2, nrm);
  // KV = gauss(ql, kp) @ vp  -> XP region (MFMA)
  gauss_av_m<0,256,1024,0,0><<<dim3(BH,4),256,0,stream>>>(
      QL, Kp, nullptr, Vp, nullptr, qln, kpn, KV);
  // Newton: 6 groups of 32 heads, packed operand flow (over dead Kp/Vp)
  for (int g = 0; g < 6; ++g){
    const float* M2g = M2 + (size_t)g*32*65536;
    pack_newtA<<<1024,256,0,stream>>>(M2g, M2Ah, M2Al);
    newton_initP<<<dim3(32,4,4),256,0,stream>>>(M2g, nrm+g*32, curAh,curAl,curBh,curBl);
    for (int it = 0; it < 6; ++it){
      mgemmP<1><<<dim3(32,4,4),256,0,stream>>>(M2Ah,M2Al,curBh,curBl,
                                               nullptr,nullptr,TsBh,TsBl,nullptr);
      if (it < 5){
        mgemmP<0><<<dim3(32,4,4),256,0,stream>>>(curAh,curAl,TsBh,TsBl,
                                                 nxtAh,nxtAl,nxtBh,nxtBl,nullptr);
        u16* t0;
        t0=curAh; curAh=nxtAh; nxtAh=t0;  t0=curAl; curAl=nxtAl; nxtAl=t0;
        t0=curBh; curBh=nxtBh; nxtBh=t0;  t0=curBl; curBl=nxtBl; nxtBl=t0;
      } else {
        mgemmP<2><<<dim3(32,4,4),256,0,stream>>>(curAh,curAl,TsBh,TsBl,
                                                 nullptr,nullptr,nullptr,nullptr,curF);
      }
    }
    bgemm<0,64><<<dim3(32,4,1),256,0,stream>>>(curF, KV + (size_t)g*32*16384,
                                               Vm + (size_t)g*32*16384);
  }
  // pack KL and Vm for the fused y kernel (KV dead; then KL dead)
  pack_bKL<<<BH*2048/256,256,0,stream>>>(KL, KLh, KLl);
  pack_bVm<<<BH*2048/256,256,0,stream>>>(Vm, Vmh, Vml);
  // y = gauss(q, kl) @ V_mixed -> Y pack (over dead M2/X packs)
  gauss_av_m<2,1025,256,1,1><<<dim3(BH,17),256,0,stream>>>(
      q, KLh, KLl, Vmh, Vml, qn, kln, (float*)Yh);
  // out = y @ proj_w^T + bias
  DUAL((proj_mfma<float><<<dim3(12,129),256,0,stream>>>(flag,0,Yh,Yl,Wph,Wpl,bp,(float*)d_out)),
       (proj_mfma<u16>  <<<dim3(12,129),256,0,stream>>>(flag,1,Yh,Yl,Wph,Wpl,bp,(u16*)d_out)));
}